// Round 3
// baseline (1806.434 us; speedup 1.0000x reference)
//
#include <hip/hip_runtime.h>

#define N_NODES 50000
#define N_EDGES 600000
#define N_GRAPHS 128
#define D 128
#define DE 64
#define N_LAYERS 4
#define BN_EPS 1e-5f
#define ECHUNK 8
#define LDST 136   // mlp LDS stride (bf16 elems), 2-dword row offset -> <=2-way conflicts
#define WST 68     // egemm LDS stride for K=64 tiles

typedef __attribute__((ext_vector_type(8))) short short8;
typedef __attribute__((ext_vector_type(4))) float floatx4;

__device__ __forceinline__ unsigned short f2bf(float f) {
    union { float f; unsigned u; } v; v.f = f;
    unsigned r = v.u + 0x7FFF + ((v.u >> 16) & 1);  // RNE
    return (unsigned short)(r >> 16);
}
__device__ __forceinline__ float bf2f(unsigned short h) {
    union { unsigned u; float f; } v; v.u = ((unsigned)h) << 16; return v.f;
}

// ================= setup: dst-sort the edge list =================
__global__ void hist_kernel(const int* __restrict__ ei, int* __restrict__ deg) {
    int e = blockIdx.x * 256 + threadIdx.x;
    if (e < N_EDGES) atomicAdd(&deg[ei[N_EDGES + e]], 1);
}

__global__ __launch_bounds__(1024) void scan_kernel(const int* __restrict__ deg,
                                                    int* __restrict__ off,
                                                    int* __restrict__ cursor) {
    __shared__ int s[1024];
    const int t = threadIdx.x;
    const int CPT = (N_NODES + 1023) / 1024;   // 49
    int base = t * CPT;
    int lim = base + CPT; if (lim > N_NODES) lim = N_NODES;
    int sum = 0;
    for (int i = base; i < lim; i++) sum += deg[i];
    s[t] = sum;
    __syncthreads();
    for (int d = 1; d < 1024; d <<= 1) {
        int v = (t >= d) ? s[t - d] : 0;
        __syncthreads();
        s[t] += v;
        __syncthreads();
    }
    int run = (t > 0) ? s[t - 1] : 0;
    for (int i = base; i < lim; i++) { off[i] = run; cursor[i] = run; run += deg[i]; }
    if (t == 1023) off[N_NODES] = s[1023];
}

__global__ void permute_kernel(const int* __restrict__ ei, int* __restrict__ cursor,
                               int* __restrict__ perm, int* __restrict__ srcp) {
    int e = blockIdx.x * 256 + threadIdx.x;
    if (e < N_EDGES) {
        int d = ei[N_EDGES + e];
        int p = atomicAdd(&cursor[d], 1);
        perm[p] = e;
        srcp[p] = ei[e];
    }
}

// ================= per-layer pass 1: E = bf16(ea[perm] @ We + be) =================
// 256 thr (4 waves); block = 64 permuted edges; MFMA 16x16x32 bf16, K=64.
__global__ __launch_bounds__(256) void egemm_kernel(
    const float* __restrict__ ea, const int* __restrict__ permc,  // perm + p0
    const float* __restrict__ We, const float* __restrict__ be,
    unsigned short* __restrict__ E, int nrows)
{
    __shared__ __align__(16) unsigned short Ws[D * WST];    // We^T [n][k]
    __shared__ __align__(16) unsigned short As[64 * WST];
    __shared__ float be_s[D];
    const int tid = threadIdx.x;

    for (int i = tid; i < DE * (D / 4); i += 256) {   // 2048
        int k = i >> 5; int n0 = (i & 31) * 4;
        float4 w = *(const float4*)(We + (size_t)k * D + n0);
        Ws[(n0 + 0) * WST + k] = f2bf(w.x);
        Ws[(n0 + 1) * WST + k] = f2bf(w.y);
        Ws[(n0 + 2) * WST + k] = f2bf(w.z);
        Ws[(n0 + 3) * WST + k] = f2bf(w.w);
    }
    if (tid < D) be_s[tid] = be[tid];

    const int row0 = blockIdx.x * 64;
    for (int i = tid; i < 64 * (DE / 4); i += 256) {  // 1024
        int r = i >> 4; int c0 = (i & 15) * 4;
        int pr = row0 + r;
        float4 v = make_float4(0.f, 0.f, 0.f, 0.f);
        if (pr < nrows) {
            int e = permc[pr];
            v = *(const float4*)(ea + (size_t)e * DE + c0);
        }
        union { unsigned short s[4]; unsigned long long u; } p;
        p.s[0] = f2bf(v.x); p.s[1] = f2bf(v.y); p.s[2] = f2bf(v.z); p.s[3] = f2bf(v.w);
        *(unsigned long long*)&As[r * WST + c0] = p.u;
    }
    __syncthreads();

    const int wave = tid >> 6, lane = tid & 63;
    const int lrow = lane & 15, lquad = lane >> 4;

    floatx4 acc[8];
#pragma unroll
    for (int ct = 0; ct < 8; ct++) acc[ct] = (floatx4){0.f, 0.f, 0.f, 0.f};
#pragma unroll
    for (int ks = 0; ks < 2; ks++) {
        short8 a = *(const short8*)&As[(wave * 16 + lrow) * WST + ks * 32 + lquad * 8];
#pragma unroll
        for (int ct = 0; ct < 8; ct++) {
            short8 b = *(const short8*)&Ws[(ct * 16 + lrow) * WST + ks * 32 + lquad * 8];
            acc[ct] = __builtin_amdgcn_mfma_f32_16x16x32_bf16(a, b, acc[ct], 0, 0, 0);
        }
    }
#pragma unroll
    for (int ct = 0; ct < 8; ct++) {
        const int c = ct * 16 + lrow;
        const float bb = be_s[c];
#pragma unroll
        for (int j = 0; j < 4; j++) {
            int pr = row0 + wave * 16 + lquad * 4 + j;
            if (pr < nrows) E[(size_t)pr * D + c] = f2bf(acc[ct][j] + bb);
        }
    }
}

// ================= per-layer pass 2: segmented accumulate =================
// agg[n] = x[n] + sum_{p in [off[n],off[n+1])} relu(x[srcp[p]] + E[p])
// 64 thr = 1 wave; thread t owns cols {2t,2t+1}; NNB nodes/block; chunk [p0,p1).
#define NNB 8
__global__ __launch_bounds__(64) void agg_kernel(
    const float* __restrict__ x, const int* __restrict__ srcp,
    const int* __restrict__ off, const unsigned short* __restrict__ E,
    float* __restrict__ agg, int p0, int p1, int isLast)
{
    const int t = threadIdx.x;
    const int n0 = blockIdx.x * NNB;
    const int nend = (n0 + NNB < N_NODES) ? n0 + NNB : N_NODES;
    for (int n = n0; n < nend; n++) {
        const int s = off[n], e = off[n + 1];
        const bool isStart = (s >= p0) && ((s < p1) || (isLast && s == N_EDGES));
        int lo = (s > p0) ? s : p0;
        int hi = (e < p1) ? e : p1;
        if (!isStart && lo >= hi) continue;
        float a0 = 0.f, a1 = 0.f;
        for (int p = lo; p < hi; p++) {
            const int sv = srcp[p];
            const unsigned u = *(const unsigned*)(E + (size_t)(p - p0) * D + 2 * t);
            float2 xv = *(const float2*)(x + (size_t)sv * D + 2 * t);
            float v0 = xv.x + bf2f((unsigned short)(u & 0xFFFF));
            float v1 = xv.y + bf2f((unsigned short)(u >> 16));
            a0 += v0 > 0.f ? v0 : 0.f;
            a1 += v1 > 0.f ? v1 : 0.f;
        }
        if (isStart) {
            float2 xs = *(const float2*)(x + (size_t)n * D + 2 * t);
            *(float2*)(agg + (size_t)n * D + 2 * t) = make_float2(xs.x + a0, xs.y + a1);
        } else {
            unsafeAtomicAdd(&agg[(size_t)n * D + 2 * t], a0);
            unsafeAtomicAdd(&agg[(size_t)n * D + 2 * t + 1], a1);
        }
    }
}

// ================= fallback edge path (small ws) =================
__global__ void copy_f4(const float4* __restrict__ src, float4* __restrict__ dst, int n4) {
    int i = blockIdx.x * blockDim.x + threadIdx.x;
    int stride = gridDim.x * blockDim.x;
    for (; i < n4; i += stride) dst[i] = src[i];
}

__global__ __launch_bounds__(128) void edge_kernel(
    const float* __restrict__ xin, const int* __restrict__ ei,
    const float* __restrict__ ea,  const float* __restrict__ We,
    const float* __restrict__ be,  float* __restrict__ agg)
{
    __shared__ float eas[ECHUNK * DE];
    const int t = threadIdx.x;
    float w[DE];
#pragma unroll
    for (int k = 0; k < DE; k++) w[k] = We[k * D + t];
    const float bias = be[t];
    const int nch = N_EDGES / ECHUNK;
    for (int ch = blockIdx.x; ch < nch; ch += gridDim.x) {
        const int e0 = ch * ECHUNK;
        ((float4*)eas)[t] = ((const float4*)(ea + (size_t)e0 * DE))[t];
        __syncthreads();
#pragma unroll
        for (int j = 0; j < ECHUNK; j++) {
            const int e = e0 + j;
            const int s = ei[e];
            const int d = ei[N_EDGES + e];
            float acc = bias;
            const float4* v4 = (const float4*)(eas + j * DE);
#pragma unroll
            for (int k4 = 0; k4 < DE / 4; k4++) {
                float4 v = v4[k4];
                acc += v.x * w[4 * k4 + 0];
                acc += v.y * w[4 * k4 + 1];
                acc += v.z * w[4 * k4 + 2];
                acc += v.w * w[4 * k4 + 3];
            }
            float msg = xin[(size_t)s * D + t] + acc;
            msg = msg > 0.f ? msg : 0.f;
            unsafeAtomicAdd(&agg[(size_t)d * D + t], msg);
        }
        __syncthreads();
    }
}

// ================= fused node MLP (512 thr, 8 waves, wave-pairs split cols) ======
__global__ __launch_bounds__(512) void mlp_kernel(
    float* __restrict__ io,
    const float* __restrict__ W1, const float* __restrict__ b1,
    const float* __restrict__ gamma, const float* __restrict__ beta,
    const float* __restrict__ rm,    const float* __restrict__ rv,
    const float* __restrict__ W2, const float* __restrict__ b2,
    int relu2)
{
    __shared__ __align__(16) unsigned short Wt1[D * LDST];
    __shared__ __align__(16) unsigned short Wt2[D * LDST];
    __shared__ __align__(16) unsigned short At[64 * LDST];
    __shared__ float alpha_s[D], betac_s[D], b2_s[D];

    const int tid = threadIdx.x;
    for (int i = tid; i < D * (D / 4); i += 512) {
        const int k = i >> 5;
        const int n0 = (i & 31) * 4;
        float4 w = *(const float4*)(W1 + (size_t)k * D + n0);
        Wt1[(n0 + 0) * LDST + k] = f2bf(w.x);
        Wt1[(n0 + 1) * LDST + k] = f2bf(w.y);
        Wt1[(n0 + 2) * LDST + k] = f2bf(w.z);
        Wt1[(n0 + 3) * LDST + k] = f2bf(w.w);
        float4 u = *(const float4*)(W2 + (size_t)k * D + n0);
        Wt2[(n0 + 0) * LDST + k] = f2bf(u.x);
        Wt2[(n0 + 1) * LDST + k] = f2bf(u.y);
        Wt2[(n0 + 2) * LDST + k] = f2bf(u.z);
        Wt2[(n0 + 3) * LDST + k] = f2bf(u.w);
    }
    if (tid < D) {
        float a = gamma[tid] * rsqrtf(rv[tid] + BN_EPS);
        alpha_s[tid] = a;
        betac_s[tid] = beta[tid] + (b1[tid] - rm[tid]) * a;
        b2_s[tid] = b2[tid];
    }
    __syncthreads();

    const int wave = tid >> 6;
    const int lane = tid & 63;
    const int lrow = lane & 15;
    const int lquad = lane >> 4;
    const int rowg = wave >> 1;     // 0..3 -> 16-row group
    const int colh = wave & 1;      // col half: ct in colh*4 .. colh*4+3

    const int ntiles = (N_NODES + 63) / 64;   // 782
    for (int g = blockIdx.x; g < ntiles; g += gridDim.x) {
        const int row0 = g * 64;
        for (int i = tid; i < 64 * (D / 4); i += 512) {
            const int r = i >> 5;
            const int c0 = (i & 31) * 4;
            const int rr = row0 + r;
            float4 v = make_float4(0.f, 0.f, 0.f, 0.f);
            if (rr < N_NODES) v = *(const float4*)(io + (size_t)rr * D + c0);
            union { unsigned short s[4]; unsigned long long u; } p;
            p.s[0] = f2bf(v.x); p.s[1] = f2bf(v.y); p.s[2] = f2bf(v.z); p.s[3] = f2bf(v.w);
            *(unsigned long long*)&At[r * LDST + c0] = p.u;
        }
        __syncthreads();

        floatx4 acc[4];
#pragma unroll
        for (int q = 0; q < 4; q++) acc[q] = (floatx4){0.f, 0.f, 0.f, 0.f};
#pragma unroll
        for (int ks = 0; ks < 4; ks++) {
            short8 a = *(const short8*)&At[(rowg * 16 + lrow) * LDST + ks * 32 + lquad * 8];
#pragma unroll
            for (int q = 0; q < 4; q++) {
                const int ct = colh * 4 + q;
                short8 b = *(const short8*)&Wt1[(ct * 16 + lrow) * LDST + ks * 32 + lquad * 8];
                acc[q] = __builtin_amdgcn_mfma_f32_16x16x32_bf16(a, b, acc[q], 0, 0, 0);
            }
        }
#pragma unroll
        for (int q = 0; q < 4; q++) {
            const int c = (colh * 4 + q) * 16 + lrow;
            const float al = alpha_s[c], bt = betac_s[c];
#pragma unroll
            for (int j = 0; j < 4; j++) {
                const int r = rowg * 16 + lquad * 4 + j;
                float v = acc[q][j] * al + bt;
                v = v > 0.f ? v : 0.f;
                At[r * LDST + c] = f2bf(v);
            }
        }
        __syncthreads();

        floatx4 acc2[4];
#pragma unroll
        for (int q = 0; q < 4; q++) acc2[q] = (floatx4){0.f, 0.f, 0.f, 0.f};
#pragma unroll
        for (int ks = 0; ks < 4; ks++) {
            short8 a = *(const short8*)&At[(rowg * 16 + lrow) * LDST + ks * 32 + lquad * 8];
#pragma unroll
            for (int q = 0; q < 4; q++) {
                const int ct = colh * 4 + q;
                short8 b = *(const short8*)&Wt2[(ct * 16 + lrow) * LDST + ks * 32 + lquad * 8];
                acc2[q] = __builtin_amdgcn_mfma_f32_16x16x32_bf16(a, b, acc2[q], 0, 0, 0);
            }
        }
#pragma unroll
        for (int q = 0; q < 4; q++) {
            const int c = (colh * 4 + q) * 16 + lrow;
            const float bb = b2_s[c];
#pragma unroll
            for (int j = 0; j < 4; j++) {
                const int r = row0 + rowg * 16 + lquad * 4 + j;
                if (r < N_NODES) {
                    float v = acc2[q][j] + bb;
                    if (relu2) v = v > 0.f ? v : 0.f;
                    io[(size_t)r * D + c] = v;
                }
            }
        }
        __syncthreads();
    }
}

// ================= pool =================
__global__ __launch_bounds__(128) void pool_kernel(
    const float* __restrict__ xin, const int* __restrict__ batch,
    float* __restrict__ out)
{
    const int g = blockIdx.x;
    const int t = threadIdx.x;
    int lo = 0, hi = N_NODES;
    while (lo < hi) { int m = (lo + hi) >> 1; if (batch[m] < g) lo = m + 1; else hi = m; }
    int lo2 = lo, hi2 = N_NODES;
    while (lo2 < hi2) { int m = (lo2 + hi2) >> 1; if (batch[m] < g + 1) lo2 = m + 1; else hi2 = m; }
    float sum = 0.f;
    for (int rr = lo; rr < lo2; rr++) sum += xin[(size_t)rr * D + t];
    const int cnt = lo2 - lo;
    out[g * D + t] = sum / (float)(cnt > 0 ? cnt : 1);
}

extern "C" void kernel_launch(void* const* d_in, const int* in_sizes, int n_in,
                              void* d_out, int out_size, void* d_ws, size_t ws_size,
                              hipStream_t stream) {
    const float* x     = (const float*)d_in[0];
    const int*   ei    = (const int*)  d_in[1];
    const float* ea    = (const float*)d_in[2];
    const int*   batch = (const int*)  d_in[3];
    const float* We    = (const float*)d_in[4];
    const float* be    = (const float*)d_in[5];
    const float* W1    = (const float*)d_in[6];
    const float* b1    = (const float*)d_in[7];
    const float* gamma = (const float*)d_in[8];
    const float* beta  = (const float*)d_in[9];
    const float* rm    = (const float*)d_in[10];
    const float* rv    = (const float*)d_in[11];
    const float* W2    = (const float*)d_in[12];
    const float* b2    = (const float*)d_in[13];
    float* out = (float*)d_out;

    char* ws = (char*)d_ws;
    size_t o = 0;
    auto alloc = [&](size_t bytes) -> char* {
        char* p = ws + o; o = (o + bytes + 255) & ~(size_t)255; return p;
    };
    float* bufA  = (float*)alloc((size_t)N_NODES * D * 4);
    float* bufB  = (float*)alloc((size_t)N_NODES * D * 4);
    int* deg     = (int*)alloc((size_t)N_NODES * 4);
    int* off     = (int*)alloc((size_t)(N_NODES + 1) * 4);
    int* cursor  = (int*)alloc((size_t)N_NODES * 4);
    int* perm    = (int*)alloc((size_t)N_EDGES * 4);
    int* srcp    = (int*)alloc((size_t)N_EDGES * 4);
    size_t remain = (ws_size > o) ? (ws_size - o) : 0;
    long maxCH = (long)(remain / ((size_t)D * 2));
    const bool fast = (maxCH >= 37504);

    const float* cur = x;
    float* nxt = bufA;
    float* other = bufB;

    if (fast) {
        int CH = (maxCH >= 150016) ? 150016 : (int)(maxCH & ~63L);
        unsigned short* E = (unsigned short*)(ws + o);
        hipMemsetAsync(deg, 0, (size_t)N_NODES * 4, stream);
        hist_kernel<<<(N_EDGES + 255) / 256, 256, 0, stream>>>(ei, deg);
        scan_kernel<<<1, 1024, 0, stream>>>(deg, off, cursor);
        permute_kernel<<<(N_EDGES + 255) / 256, 256, 0, stream>>>(ei, cursor, perm, srcp);

        for (int i = 0; i < N_LAYERS; i++) {
            const float* Wel = We + (size_t)i * DE * D;
            const float* bel = be + (size_t)i * D;
            for (int p0 = 0; p0 < N_EDGES; p0 += CH) {
                int p1 = (p0 + CH < N_EDGES) ? p0 + CH : N_EDGES;
                int nrows = p1 - p0;
                egemm_kernel<<<(nrows + 63) / 64, 256, 0, stream>>>(ea, perm + p0, Wel, bel, E, nrows);
                agg_kernel<<<(N_NODES + NNB - 1) / NNB, 64, 0, stream>>>(
                    cur, srcp, off, E, nxt, p0, p1, (p1 == N_EDGES) ? 1 : 0);
            }
            mlp_kernel<<<256, 512, 0, stream>>>(nxt,
                W1 + (size_t)i * D * D, b1 + (size_t)i * D,
                gamma + (size_t)i * D, beta + (size_t)i * D,
                rm + (size_t)i * D, rv + (size_t)i * D,
                W2 + (size_t)i * D * D, b2 + (size_t)i * D,
                (i != N_LAYERS - 1) ? 1 : 0);
            cur = nxt;
            float* t = nxt == bufA ? bufB : bufA;
            other = nxt; nxt = t;
        }
    } else {
        for (int i = 0; i < N_LAYERS; i++) {
            copy_f4<<<1024, 256, 0, stream>>>((const float4*)cur, (float4*)nxt, N_NODES * D / 4);
            edge_kernel<<<4096, 128, 0, stream>>>(cur, ei, ea, We + (size_t)i * DE * D, be + (size_t)i * D, nxt);
            mlp_kernel<<<256, 512, 0, stream>>>(nxt,
                W1 + (size_t)i * D * D, b1 + (size_t)i * D,
                gamma + (size_t)i * D, beta + (size_t)i * D,
                rm + (size_t)i * D, rv + (size_t)i * D,
                W2 + (size_t)i * D * D, b2 + (size_t)i * D,
                (i != N_LAYERS - 1) ? 1 : 0);
            cur = nxt;
            float* t = nxt == bufA ? bufB : bufA;
            other = nxt; nxt = t;
        }
    }
    pool_kernel<<<N_GRAPHS, D, 0, stream>>>(cur, batch, out);
}

// Round 4
// 1364.294 us; speedup vs baseline: 1.3241x; 1.3241x over previous
//
#include <hip/hip_runtime.h>

#define N_NODES 50000
#define N_EDGES 600000
#define N_GRAPHS 128
#define D 128
#define DE 64
#define N_LAYERS 4
#define BN_EPS 1e-5f
#define ECHUNK 8
#define LDST 136   // mlp LDS stride (bf16 elems)
#define WST 68     // K=64 LDS stride (bf16 elems)
#define CTS 132    // edge C-tile stride (bf16 elems): 66 dwords -> 2-way max
#define ET 128     // edges per tile

typedef __attribute__((ext_vector_type(8))) short short8;
typedef __attribute__((ext_vector_type(4))) float floatx4;

__device__ __forceinline__ unsigned short f2bf(float f) {
    union { float f; unsigned u; } v; v.f = f;
    unsigned r = v.u + 0x7FFF + ((v.u >> 16) & 1);  // RNE
    return (unsigned short)(r >> 16);
}
__device__ __forceinline__ float bf2f(unsigned short h) {
    union { unsigned u; float f; } v; v.u = ((unsigned)h) << 16; return v.f;
}

// ================= setup: dst-sort =================
__global__ void hist_kernel(const int* __restrict__ ei, int* __restrict__ deg) {
    int e = blockIdx.x * 256 + threadIdx.x;
    if (e < N_EDGES) atomicAdd(&deg[ei[N_EDGES + e]], 1);
}

__global__ void scan1_kernel(const int* __restrict__ deg, int* __restrict__ bsum) {
    __shared__ int s[256];
    int t = threadIdx.x, i = blockIdx.x * 256 + t;
    s[t] = (i < N_NODES) ? deg[i] : 0;
    __syncthreads();
    for (int d = 128; d > 0; d >>= 1) {
        if (t < d) s[t] += s[t + d];
        __syncthreads();
    }
    if (t == 0) bsum[blockIdx.x] = s[0];
}

__global__ void scan2_kernel(int* __restrict__ bsum, int nb) {
    __shared__ int s[256];
    int t = threadIdx.x;
    int v = (t < nb) ? bsum[t] : 0;
    s[t] = v;
    __syncthreads();
    for (int d = 1; d < 256; d <<= 1) {
        int u = (t >= d) ? s[t - d] : 0;
        __syncthreads();
        s[t] += u;
        __syncthreads();
    }
    if (t < nb) bsum[t] = s[t] - v;   // exclusive
}

__global__ void scan3_kernel(const int* __restrict__ deg, const int* __restrict__ bsum,
                             int* __restrict__ off, int* __restrict__ cursor) {
    __shared__ int s[256];
    int t = threadIdx.x, i = blockIdx.x * 256 + t;
    int v = (i < N_NODES) ? deg[i] : 0;
    s[t] = v;
    __syncthreads();
    for (int d = 1; d < 256; d <<= 1) {
        int u = (t >= d) ? s[t - d] : 0;
        __syncthreads();
        s[t] += u;
        __syncthreads();
    }
    if (i < N_NODES) {
        int o = bsum[blockIdx.x] + s[t] - v;
        off[i] = o; cursor[i] = o;
    }
    if (i == N_NODES - 1) off[N_NODES] = bsum[blockIdx.x] + s[t];
}

__global__ void permute_kernel(const int* __restrict__ ei, int* __restrict__ cursor,
                               int* __restrict__ perm, int* __restrict__ srcp,
                               int* __restrict__ dstp) {
    int e = blockIdx.x * 256 + threadIdx.x;
    if (e < N_EDGES) {
        int d = ei[N_EDGES + e];
        int p = atomicAdd(&cursor[d], 1);
        perm[p] = e; srcp[p] = ei[e]; dstp[p] = d;
    }
}

// build dst-sorted bf16 edge_attr
__global__ void eap_kernel(const float* __restrict__ ea, const int* __restrict__ perm,
                           unsigned short* __restrict__ eap) {
    int i = blockIdx.x * 256 + threadIdx.x;
    if (i >= N_EDGES * 16) return;
    int p = i >> 4, c0 = (i & 15) * 4;
    int e = perm[p];
    float4 v = *(const float4*)(ea + (size_t)e * DE + c0);
    union { unsigned short s[4]; unsigned long long u; } pk;
    pk.s[0] = f2bf(v.x); pk.s[1] = f2bf(v.y); pk.s[2] = f2bf(v.z); pk.s[3] = f2bf(v.w);
    *(unsigned long long*)(eap + (size_t)p * DE + c0) = pk.u;
}

// ================= fused edge layer =================
// agg[dst] += relu(x[src] + ea@We + be) over dst-sorted 128-edge tiles.
__global__ __launch_bounds__(256) void edge_fused(
    const float* __restrict__ x,
    const float* __restrict__ ea,
    const unsigned short* __restrict__ eap,
    const int* __restrict__ perm,
    const int* __restrict__ srcp,
    const int* __restrict__ dstp,
    const float* __restrict__ We, const float* __restrict__ be,
    float* __restrict__ agg, int useEap)
{
    __shared__ __align__(16) unsigned short Wt[D * WST];    // We^T [n][k]
    __shared__ __align__(16) unsigned short As[ET * WST];
    __shared__ __align__(16) unsigned short Ct[ET * CTS];   // e = A@We + be (bf16)
    __shared__ int srcs[ET];
    __shared__ int dsts[ET];
    __shared__ float be_s[D];

    const int tid = threadIdx.x;
    for (int i = tid; i < DE * (D / 4); i += 256) {
        int k = i >> 5, n0 = (i & 31) * 4;
        float4 w = *(const float4*)(We + (size_t)k * D + n0);
        Wt[(n0 + 0) * WST + k] = f2bf(w.x);
        Wt[(n0 + 1) * WST + k] = f2bf(w.y);
        Wt[(n0 + 2) * WST + k] = f2bf(w.z);
        Wt[(n0 + 3) * WST + k] = f2bf(w.w);
    }
    if (tid < D) be_s[tid] = be[tid];

    const int wave = tid >> 6, lane = tid & 63;
    const int lrow = lane & 15, lquad = lane >> 4;
    const int waveBase = wave * 32;
    const int cp = lane;                 // col pair {2cp, 2cp+1}

    const int ntiles = (N_EDGES + ET - 1) / ET;
    for (int g = blockIdx.x; g < ntiles; g += gridDim.x) {
        const int p0 = g * ET;
        const int nv = (N_EDGES - p0 < ET) ? (N_EDGES - p0) : ET;
        if (tid < ET) {
            int ok = tid < nv;
            srcs[tid] = ok ? srcp[p0 + tid] : 0;
            dsts[tid] = ok ? dstp[p0 + tid] : -1;
        }
        if (useEap) {
            for (int i = tid; i < ET * 16; i += 256) {
                int r = i >> 4, c0 = (i & 15) * 4;
                unsigned long long v = 0;
                if (r < nv) v = *(const unsigned long long*)(eap + (size_t)(p0 + r) * DE + c0);
                *(unsigned long long*)&As[r * WST + c0] = v;
            }
        } else {
            for (int i = tid; i < ET * 16; i += 256) {
                int r = i >> 4, c0 = (i & 15) * 4;
                float4 v = make_float4(0.f, 0.f, 0.f, 0.f);
                if (r < nv) {
                    int e = perm[p0 + r];
                    v = *(const float4*)(ea + (size_t)e * DE + c0);
                }
                union { unsigned short s[4]; unsigned long long u; } pk;
                pk.s[0] = f2bf(v.x); pk.s[1] = f2bf(v.y); pk.s[2] = f2bf(v.z); pk.s[3] = f2bf(v.w);
                *(unsigned long long*)&As[r * WST + c0] = pk.u;
            }
        }
        __syncthreads();

        floatx4 acc[2][8];
#pragma unroll
        for (int rg = 0; rg < 2; rg++)
#pragma unroll
            for (int ct = 0; ct < 8; ct++) acc[rg][ct] = (floatx4){0.f, 0.f, 0.f, 0.f};
#pragma unroll
        for (int rg = 0; rg < 2; rg++) {
            const int Ar = waveBase + rg * 16 + lrow;
#pragma unroll
            for (int ks = 0; ks < 2; ks++) {
                short8 a = *(const short8*)&As[Ar * WST + ks * 32 + lquad * 8];
#pragma unroll
                for (int ct = 0; ct < 8; ct++) {
                    short8 b = *(const short8*)&Wt[(ct * 16 + lrow) * WST + ks * 32 + lquad * 8];
                    acc[rg][ct] = __builtin_amdgcn_mfma_f32_16x16x32_bf16(a, b, acc[rg][ct], 0, 0, 0);
                }
            }
        }
        // C layout: col = ct*16 + (lane&15), row = waveBase + rg*16 + lquad*4 + j
#pragma unroll
        for (int rg = 0; rg < 2; rg++)
#pragma unroll
            for (int ct = 0; ct < 8; ct++) {
                const int c = ct * 16 + lrow;
                const float bb = be_s[c];
#pragma unroll
                for (int j = 0; j < 4; j++) {
                    const int r = waveBase + rg * 16 + lquad * 4 + j;
                    Ct[r * CTS + c] = f2bf(acc[rg][ct][j] + bb);
                }
            }
        __syncthreads();

        // segmented accumulate: wave owns rows [wave*32, wave*32+32), lane owns 2 cols
        {
            const int rlo = wave * 32;
            int rhi = rlo + 32; if (rhi > nv) rhi = nv;
            float a0 = 0.f, a1 = 0.f;
            if (rlo < rhi) {
                int r = rlo;
                unsigned ed = *(const unsigned*)&Ct[r * CTS + 2 * cp];
                float2 xv = *(const float2*)(x + (size_t)srcs[r] * D + 2 * cp);
                for (; r < rhi; r++) {
                    unsigned edn = 0; float2 xn = make_float2(0.f, 0.f);
                    if (r + 1 < rhi) {
                        edn = *(const unsigned*)&Ct[(r + 1) * CTS + 2 * cp];
                        xn = *(const float2*)(x + (size_t)srcs[r + 1] * D + 2 * cp);
                    }
                    float v0 = xv.x + bf2f((unsigned short)(ed & 0xFFFF));
                    float v1 = xv.y + bf2f((unsigned short)(ed >> 16));
                    a0 += v0 > 0.f ? v0 : 0.f;
                    a1 += v1 > 0.f ? v1 : 0.f;
                    if (r + 1 == rhi || dsts[r + 1] != dsts[r]) {   // wave-uniform
                        float* ap = agg + (size_t)dsts[r] * D + 2 * cp;
                        unsafeAtomicAdd(ap, a0);
                        unsafeAtomicAdd(ap + 1, a1);
                        a0 = 0.f; a1 = 0.f;
                    }
                    ed = edn; xv = xn;
                }
            }
        }
        __syncthreads();
    }
}

// ================= fallback edge path =================
__global__ void copy_f4(const float4* __restrict__ src, float4* __restrict__ dst, int n4) {
    int i = blockIdx.x * blockDim.x + threadIdx.x;
    int stride = gridDim.x * blockDim.x;
    for (; i < n4; i += stride) dst[i] = src[i];
}

__global__ __launch_bounds__(128) void edge_kernel(
    const float* __restrict__ xin, const int* __restrict__ ei,
    const float* __restrict__ ea,  const float* __restrict__ We,
    const float* __restrict__ be,  float* __restrict__ agg)
{
    __shared__ float eas[ECHUNK * DE];
    const int t = threadIdx.x;
    float w[DE];
#pragma unroll
    for (int k = 0; k < DE; k++) w[k] = We[k * D + t];
    const float bias = be[t];
    const int nch = N_EDGES / ECHUNK;
    for (int ch = blockIdx.x; ch < nch; ch += gridDim.x) {
        const int e0 = ch * ECHUNK;
        ((float4*)eas)[t] = ((const float4*)(ea + (size_t)e0 * DE))[t];
        __syncthreads();
#pragma unroll
        for (int j = 0; j < ECHUNK; j++) {
            const int e = e0 + j;
            const int s = ei[e];
            const int d = ei[N_EDGES + e];
            float acc = bias;
            const float4* v4 = (const float4*)(eas + j * DE);
#pragma unroll
            for (int k4 = 0; k4 < DE / 4; k4++) {
                float4 v = v4[k4];
                acc += v.x * w[4 * k4 + 0];
                acc += v.y * w[4 * k4 + 1];
                acc += v.z * w[4 * k4 + 2];
                acc += v.w * w[4 * k4 + 3];
            }
            float msg = xin[(size_t)s * D + t] + acc;
            msg = msg > 0.f ? msg : 0.f;
            unsafeAtomicAdd(&agg[(size_t)d * D + t], msg);
        }
        __syncthreads();
    }
}

// ================= fused node MLP (512 thr), optional dual-store ======
__global__ __launch_bounds__(512) void mlp_kernel(
    float* __restrict__ io,
    const float* __restrict__ W1, const float* __restrict__ b1,
    const float* __restrict__ gamma, const float* __restrict__ beta,
    const float* __restrict__ rm,    const float* __restrict__ rv,
    const float* __restrict__ W2, const float* __restrict__ b2,
    float* __restrict__ agg2, int relu2)
{
    __shared__ __align__(16) unsigned short Wt1[D * LDST];
    __shared__ __align__(16) unsigned short Wt2[D * LDST];
    __shared__ __align__(16) unsigned short At[64 * LDST];
    __shared__ float alpha_s[D], betac_s[D], b2_s[D];

    const int tid = threadIdx.x;
    for (int i = tid; i < D * (D / 4); i += 512) {
        const int k = i >> 5;
        const int n0 = (i & 31) * 4;
        float4 w = *(const float4*)(W1 + (size_t)k * D + n0);
        Wt1[(n0 + 0) * LDST + k] = f2bf(w.x);
        Wt1[(n0 + 1) * LDST + k] = f2bf(w.y);
        Wt1[(n0 + 2) * LDST + k] = f2bf(w.z);
        Wt1[(n0 + 3) * LDST + k] = f2bf(w.w);
        float4 u = *(const float4*)(W2 + (size_t)k * D + n0);
        Wt2[(n0 + 0) * LDST + k] = f2bf(u.x);
        Wt2[(n0 + 1) * LDST + k] = f2bf(u.y);
        Wt2[(n0 + 2) * LDST + k] = f2bf(u.z);
        Wt2[(n0 + 3) * LDST + k] = f2bf(u.w);
    }
    if (tid < D) {
        float a = gamma[tid] * rsqrtf(rv[tid] + BN_EPS);
        alpha_s[tid] = a;
        betac_s[tid] = beta[tid] + (b1[tid] - rm[tid]) * a;
        b2_s[tid] = b2[tid];
    }
    __syncthreads();

    const int wave = tid >> 6;
    const int lane = tid & 63;
    const int lrow = lane & 15;
    const int lquad = lane >> 4;
    const int rowg = wave >> 1;
    const int colh = wave & 1;

    const int ntiles = (N_NODES + 63) / 64;
    for (int g = blockIdx.x; g < ntiles; g += gridDim.x) {
        const int row0 = g * 64;
        for (int i = tid; i < 64 * (D / 4); i += 512) {
            const int r = i >> 5;
            const int c0 = (i & 31) * 4;
            const int rr = row0 + r;
            float4 v = make_float4(0.f, 0.f, 0.f, 0.f);
            if (rr < N_NODES) v = *(const float4*)(io + (size_t)rr * D + c0);
            union { unsigned short s[4]; unsigned long long u; } p;
            p.s[0] = f2bf(v.x); p.s[1] = f2bf(v.y); p.s[2] = f2bf(v.z); p.s[3] = f2bf(v.w);
            *(unsigned long long*)&At[r * LDST + c0] = p.u;
        }
        __syncthreads();

        floatx4 acc[4];
#pragma unroll
        for (int q = 0; q < 4; q++) acc[q] = (floatx4){0.f, 0.f, 0.f, 0.f};
#pragma unroll
        for (int ks = 0; ks < 4; ks++) {
            short8 a = *(const short8*)&At[(rowg * 16 + lrow) * LDST + ks * 32 + lquad * 8];
#pragma unroll
            for (int q = 0; q < 4; q++) {
                const int ct = colh * 4 + q;
                short8 b = *(const short8*)&Wt1[(ct * 16 + lrow) * LDST + ks * 32 + lquad * 8];
                acc[q] = __builtin_amdgcn_mfma_f32_16x16x32_bf16(a, b, acc[q], 0, 0, 0);
            }
        }
#pragma unroll
        for (int q = 0; q < 4; q++) {
            const int c = (colh * 4 + q) * 16 + lrow;
            const float al = alpha_s[c], bt = betac_s[c];
#pragma unroll
            for (int j = 0; j < 4; j++) {
                const int r = rowg * 16 + lquad * 4 + j;
                float v = acc[q][j] * al + bt;
                v = v > 0.f ? v : 0.f;
                At[r * LDST + c] = f2bf(v);
            }
        }
        __syncthreads();

        floatx4 acc2[4];
#pragma unroll
        for (int q = 0; q < 4; q++) acc2[q] = (floatx4){0.f, 0.f, 0.f, 0.f};
#pragma unroll
        for (int ks = 0; ks < 4; ks++) {
            short8 a = *(const short8*)&At[(rowg * 16 + lrow) * LDST + ks * 32 + lquad * 8];
#pragma unroll
            for (int q = 0; q < 4; q++) {
                const int ct = colh * 4 + q;
                short8 b = *(const short8*)&Wt2[(ct * 16 + lrow) * LDST + ks * 32 + lquad * 8];
                acc2[q] = __builtin_amdgcn_mfma_f32_16x16x32_bf16(a, b, acc2[q], 0, 0, 0);
            }
        }
#pragma unroll
        for (int q = 0; q < 4; q++) {
            const int c = (colh * 4 + q) * 16 + lrow;
            const float bb = b2_s[c];
#pragma unroll
            for (int j = 0; j < 4; j++) {
                const int r = row0 + rowg * 16 + lquad * 4 + j;
                if (r < N_NODES) {
                    float v = acc2[q][j] + bb;
                    if (relu2) v = v > 0.f ? v : 0.f;
                    io[(size_t)r * D + c] = v;
                    if (agg2) agg2[(size_t)r * D + c] = v;
                }
            }
        }
        __syncthreads();
    }
}

// ================= pool =================
__global__ __launch_bounds__(128) void pool_kernel(
    const float* __restrict__ xin, const int* __restrict__ batch,
    float* __restrict__ out)
{
    const int g = blockIdx.x;
    const int t = threadIdx.x;
    int lo = 0, hi = N_NODES;
    while (lo < hi) { int m = (lo + hi) >> 1; if (batch[m] < g) lo = m + 1; else hi = m; }
    int lo2 = lo, hi2 = N_NODES;
    while (lo2 < hi2) { int m = (lo2 + hi2) >> 1; if (batch[m] < g + 1) lo2 = m + 1; else hi2 = m; }
    float sum = 0.f;
    for (int rr = lo; rr < lo2; rr++) sum += xin[(size_t)rr * D + t];
    const int cnt = lo2 - lo;
    out[g * D + t] = sum / (float)(cnt > 0 ? cnt : 1);
}

extern "C" void kernel_launch(void* const* d_in, const int* in_sizes, int n_in,
                              void* d_out, int out_size, void* d_ws, size_t ws_size,
                              hipStream_t stream) {
    const float* x     = (const float*)d_in[0];
    const int*   ei    = (const int*)  d_in[1];
    const float* ea    = (const float*)d_in[2];
    const int*   batch = (const int*)  d_in[3];
    const float* We    = (const float*)d_in[4];
    const float* be    = (const float*)d_in[5];
    const float* W1    = (const float*)d_in[6];
    const float* b1    = (const float*)d_in[7];
    const float* gamma = (const float*)d_in[8];
    const float* beta  = (const float*)d_in[9];
    const float* rm    = (const float*)d_in[10];
    const float* rv    = (const float*)d_in[11];
    const float* W2    = (const float*)d_in[12];
    const float* b2    = (const float*)d_in[13];
    float* out = (float*)d_out;

    char* ws = (char*)d_ws;
    size_t o = 0;
    auto alloc = [&](size_t bytes) -> char* {
        char* p = ws + o; o = (o + bytes + 255) & ~(size_t)255; return p;
    };
    float* bufA  = (float*)alloc((size_t)N_NODES * D * 4);
    float* bufB  = (float*)alloc((size_t)N_NODES * D * 4);
    int* deg     = (int*)alloc((size_t)N_NODES * 4);
    int* off     = (int*)alloc((size_t)(N_NODES + 1) * 4);
    int* cursor  = (int*)alloc((size_t)N_NODES * 4);
    int* perm    = (int*)alloc((size_t)N_EDGES * 4);
    int* srcp    = (int*)alloc((size_t)N_EDGES * 4);
    int* dstp    = (int*)alloc((size_t)N_EDGES * 4);
    int* bsum    = (int*)alloc(256 * 4);
    const size_t needSorted = o;
    unsigned short* eap = nullptr;
    if (ws_size >= needSorted + (size_t)N_EDGES * DE * 2)
        eap = (unsigned short*)(ws + needSorted);
    const bool sorted = (ws_size >= needSorted);

    const int NB = (N_NODES + 255) / 256;   // 196

    if (sorted) {
        hipMemsetAsync(deg, 0, (size_t)N_NODES * 4, stream);
        hist_kernel<<<(N_EDGES + 255) / 256, 256, 0, stream>>>(ei, deg);
        scan1_kernel<<<NB, 256, 0, stream>>>(deg, bsum);
        scan2_kernel<<<1, 256, 0, stream>>>(bsum, NB);
        scan3_kernel<<<NB, 256, 0, stream>>>(deg, bsum, off, cursor);
        permute_kernel<<<(N_EDGES + 255) / 256, 256, 0, stream>>>(ei, cursor, perm, srcp, dstp);
        if (eap) eap_kernel<<<(N_EDGES * 16) / 256, 256, 0, stream>>>(ea, perm, eap);

        const float* cur = x;
        float* agg = bufA;
        float* nxtAgg = bufB;
        copy_f4<<<1024, 256, 0, stream>>>((const float4*)x, (float4*)agg, N_NODES * D / 4);
        for (int i = 0; i < N_LAYERS; i++) {
            edge_fused<<<512, 256, 0, stream>>>(cur, ea, eap, perm, srcp, dstp,
                                                We + (size_t)i * DE * D, be + (size_t)i * D,
                                                agg, eap ? 1 : 0);
            mlp_kernel<<<256, 512, 0, stream>>>(agg,
                W1 + (size_t)i * D * D, b1 + (size_t)i * D,
                gamma + (size_t)i * D, beta + (size_t)i * D,
                rm + (size_t)i * D, rv + (size_t)i * D,
                W2 + (size_t)i * D * D, b2 + (size_t)i * D,
                (i != N_LAYERS - 1) ? nxtAgg : nullptr,
                (i != N_LAYERS - 1) ? 1 : 0);
            cur = agg;
            agg = nxtAgg;
            nxtAgg = (float*)cur;
        }
        pool_kernel<<<N_GRAPHS, D, 0, stream>>>(cur, batch, out);
    } else {
        const float* cur = x;
        float* nxt = bufA;
        float* oth = bufB;
        for (int i = 0; i < N_LAYERS; i++) {
            copy_f4<<<1024, 256, 0, stream>>>((const float4*)cur, (float4*)nxt, N_NODES * D / 4);
            edge_kernel<<<4096, 128, 0, stream>>>(cur, ei, ea, We + (size_t)i * DE * D, be + (size_t)i * D, nxt);
            mlp_kernel<<<256, 512, 0, stream>>>(nxt,
                W1 + (size_t)i * D * D, b1 + (size_t)i * D,
                gamma + (size_t)i * D, beta + (size_t)i * D,
                rm + (size_t)i * D, rv + (size_t)i * D,
                W2 + (size_t)i * D * D, b2 + (size_t)i * D,
                nullptr, (i != N_LAYERS - 1) ? 1 : 0);
            cur = nxt;
            float* t = (nxt == bufA) ? bufB : bufA;
            oth = nxt; nxt = t;
        }
        pool_kernel<<<N_GRAPHS, D, 0, stream>>>(cur, batch, out);
    }
}

// Round 5
// 876.805 us; speedup vs baseline: 2.0602x; 1.5560x over previous
//
#include <hip/hip_runtime.h>

#define N_NODES 50000
#define N_EDGES 600000
#define N_GRAPHS 128
#define D 128
#define DE 64
#define N_LAYERS 4
#define BN_EPS 1e-5f
#define ECHUNK 8
#define LDST 136   // mlp LDS stride (bf16): 272 B rows, 16B-aligned, chunk-stride 17%8=1
#define WST 72     // K=64 LDS stride (bf16): 144 B rows, 16B-aligned, chunk-stride 9%8=1
#define CTS 132    // edge C-tile stride (bf16): dword-per-lane reads conflict-free
#define ET 128     // edges per tile

typedef __attribute__((ext_vector_type(8))) short short8;
typedef __attribute__((ext_vector_type(4))) float floatx4;

__device__ __forceinline__ unsigned short f2bf(float f) {
    union { float f; unsigned u; } v; v.f = f;
    unsigned r = v.u + 0x7FFF + ((v.u >> 16) & 1);  // RNE
    return (unsigned short)(r >> 16);
}
__device__ __forceinline__ float bf2f(unsigned short h) {
    union { unsigned u; float f; } v; v.u = ((unsigned)h) << 16; return v.f;
}

// ================= setup: dst-sort =================
__global__ void hist_kernel(const int* __restrict__ ei, int* __restrict__ deg) {
    int e = blockIdx.x * 256 + threadIdx.x;
    if (e < N_EDGES) atomicAdd(&deg[ei[N_EDGES + e]], 1);
}

__global__ void scan1_kernel(const int* __restrict__ deg, int* __restrict__ bsum) {
    __shared__ int s[256];
    int t = threadIdx.x, i = blockIdx.x * 256 + t;
    s[t] = (i < N_NODES) ? deg[i] : 0;
    __syncthreads();
    for (int d = 128; d > 0; d >>= 1) {
        if (t < d) s[t] += s[t + d];
        __syncthreads();
    }
    if (t == 0) bsum[blockIdx.x] = s[0];
}

__global__ void scan2_kernel(int* __restrict__ bsum, int nb) {
    __shared__ int s[256];
    int t = threadIdx.x;
    int v = (t < nb) ? bsum[t] : 0;
    s[t] = v;
    __syncthreads();
    for (int d = 1; d < 256; d <<= 1) {
        int u = (t >= d) ? s[t - d] : 0;
        __syncthreads();
        s[t] += u;
        __syncthreads();
    }
    if (t < nb) bsum[t] = s[t] - v;   // exclusive
}

__global__ void scan3_kernel(const int* __restrict__ deg, const int* __restrict__ bsum,
                             int* __restrict__ off, int* __restrict__ cursor) {
    __shared__ int s[256];
    int t = threadIdx.x, i = blockIdx.x * 256 + t;
    int v = (i < N_NODES) ? deg[i] : 0;
    s[t] = v;
    __syncthreads();
    for (int d = 1; d < 256; d <<= 1) {
        int u = (t >= d) ? s[t - d] : 0;
        __syncthreads();
        s[t] += u;
        __syncthreads();
    }
    if (i < N_NODES) {
        int o = bsum[blockIdx.x] + s[t] - v;
        off[i] = o; cursor[i] = o;
    }
    if (i == N_NODES - 1) off[N_NODES] = bsum[blockIdx.x] + s[t];
}

__global__ void permute_kernel(const int* __restrict__ ei, int* __restrict__ cursor,
                               int* __restrict__ perm, int* __restrict__ srcp,
                               int* __restrict__ dstp) {
    int e = blockIdx.x * 256 + threadIdx.x;
    if (e < N_EDGES) {
        int d = ei[N_EDGES + e];
        int p = atomicAdd(&cursor[d], 1);
        perm[p] = e; srcp[p] = ei[e]; dstp[p] = d;
    }
}

// build dst-sorted bf16 edge_attr
__global__ void eap_kernel(const float* __restrict__ ea, const int* __restrict__ perm,
                           unsigned short* __restrict__ eap) {
    int i = blockIdx.x * 256 + threadIdx.x;
    if (i >= N_EDGES * 16) return;
    int p = i >> 4, c0 = (i & 15) * 4;
    int e = perm[p];
    float4 v = *(const float4*)(ea + (size_t)e * DE + c0);
    union { unsigned short s[4]; unsigned long long u; } pk;
    pk.s[0] = f2bf(v.x); pk.s[1] = f2bf(v.y); pk.s[2] = f2bf(v.z); pk.s[3] = f2bf(v.w);
    *(unsigned long long*)(eap + (size_t)p * DE + c0) = pk.u;
}

// ================= fused edge layer =================
// agg[dst] += relu(x[src] + ea@We + be) over dst-sorted 128-edge tiles.
// 512 thr / 8 waves; wave owns 16 rows; batched register preload of x-gather.
__global__ __launch_bounds__(512, 4) void edge_fused(
    const float* __restrict__ x,
    const float* __restrict__ ea,
    const unsigned short* __restrict__ eap,
    const int* __restrict__ perm,
    const int* __restrict__ srcp,
    const int* __restrict__ dstp,
    const float* __restrict__ We, const float* __restrict__ be,
    float* __restrict__ agg, int useEap)
{
    __shared__ __align__(16) unsigned short Wt[D * WST];    // We^T [n][k]
    __shared__ __align__(16) unsigned short As[ET * WST];
    __shared__ __align__(16) unsigned short Ct[ET * CTS];   // e = A@We + be (bf16)
    __shared__ int srcs[ET];
    __shared__ int dsts[ET];
    __shared__ float be_s[D];

    const int tid = threadIdx.x;
    for (int i = tid; i < DE * (D / 4); i += 512) {
        int k = i >> 5, n0 = (i & 31) * 4;
        float4 w = *(const float4*)(We + (size_t)k * D + n0);
        Wt[(n0 + 0) * WST + k] = f2bf(w.x);
        Wt[(n0 + 1) * WST + k] = f2bf(w.y);
        Wt[(n0 + 2) * WST + k] = f2bf(w.z);
        Wt[(n0 + 3) * WST + k] = f2bf(w.w);
    }
    if (tid < D) be_s[tid] = be[tid];

    const int wave = tid >> 6, lane = tid & 63;
    const int lrow = lane & 15, lquad = lane >> 4;
    const int cp = lane;                 // col pair {2cp, 2cp+1}

    const int ntiles = (N_EDGES + ET - 1) / ET;
    for (int g = blockIdx.x; g < ntiles; g += gridDim.x) {
        const int p0 = g * ET;
        const int nv = (N_EDGES - p0 < ET) ? (N_EDGES - p0) : ET;   // 128 or 64 (multiple of 16)
        if (tid < ET) {
            int ok = tid < nv;
            srcs[tid] = ok ? srcp[p0 + tid] : 0;
            dsts[tid] = ok ? dstp[p0 + tid] : -1;
        }
        if (useEap) {
            for (int i = tid; i < ET * 16; i += 512) {
                int r = i >> 4, c0 = (i & 15) * 4;
                unsigned long long v = 0;
                if (r < nv) v = *(const unsigned long long*)(eap + (size_t)(p0 + r) * DE + c0);
                *(unsigned long long*)&As[r * WST + c0] = v;
            }
        } else {
            for (int i = tid; i < ET * 16; i += 512) {
                int r = i >> 4, c0 = (i & 15) * 4;
                float4 v = make_float4(0.f, 0.f, 0.f, 0.f);
                if (r < nv) {
                    int e = perm[p0 + r];
                    v = *(const float4*)(ea + (size_t)e * DE + c0);
                }
                union { unsigned short s[4]; unsigned long long u; } pk;
                pk.s[0] = f2bf(v.x); pk.s[1] = f2bf(v.y); pk.s[2] = f2bf(v.z); pk.s[3] = f2bf(v.w);
                *(unsigned long long*)&As[r * WST + c0] = pk.u;
            }
        }
        __syncthreads();

        // ---- MFMA: wave's 16 rows x 128 cols ----
        const int rlo = wave * 16;
        {
            floatx4 acc[8];
#pragma unroll
            for (int ct = 0; ct < 8; ct++) acc[ct] = (floatx4){0.f, 0.f, 0.f, 0.f};
#pragma unroll
            for (int ks = 0; ks < 2; ks++) {
                short8 a = *(const short8*)&As[(rlo + lrow) * WST + ks * 32 + lquad * 8];
#pragma unroll
                for (int ct = 0; ct < 8; ct++) {
                    short8 b = *(const short8*)&Wt[(ct * 16 + lrow) * WST + ks * 32 + lquad * 8];
                    acc[ct] = __builtin_amdgcn_mfma_f32_16x16x32_bf16(a, b, acc[ct], 0, 0, 0);
                }
            }
            // C layout: col = ct*16 + lrow, row = rlo + lquad*4 + j  (own wave rows only)
#pragma unroll
            for (int ct = 0; ct < 8; ct++) {
                const int c = ct * 16 + lrow;
                const float bb = be_s[c];
#pragma unroll
                for (int j = 0; j < 4; j++) {
                    const int r = rlo + lquad * 4 + j;
                    Ct[r * CTS + c] = f2bf(acc[ct][j] + bb);
                }
            }
        }
        // no barrier needed: wave reads back only its own Ct rows (lgkmcnt handles RAW)

        // ---- segmented accumulate: 16 batched independent loads, then reduce ----
        if (rlo < nv) {
            unsigned ed[16];
            float2 xv[16];
#pragma unroll
            for (int j = 0; j < 16; j++)
                ed[j] = *(const unsigned*)&Ct[(rlo + j) * CTS + 2 * cp];
#pragma unroll
            for (int j = 0; j < 16; j++)
                xv[j] = *(const float2*)(x + (size_t)srcs[rlo + j] * D + 2 * cp);
            float a0 = 0.f, a1 = 0.f;
            int dprev = dsts[rlo];
#pragma unroll
            for (int j = 0; j < 16; j++) {
                float v0 = xv[j].x + bf2f((unsigned short)(ed[j] & 0xFFFF));
                float v1 = xv[j].y + bf2f((unsigned short)(ed[j] >> 16));
                a0 += v0 > 0.f ? v0 : 0.f;
                a1 += v1 > 0.f ? v1 : 0.f;
                int dnext = (j < 15) ? dsts[rlo + j + 1] : -2;   // wave-uniform LDS broadcast
                if (dnext != dprev) {
                    float* ap = agg + (size_t)dprev * D + 2 * cp;
                    unsafeAtomicAdd(ap, a0);
                    unsafeAtomicAdd(ap + 1, a1);
                    a0 = 0.f; a1 = 0.f;
                    dprev = dnext;
                }
            }
        }
        __syncthreads();   // protect As/Ct/srcs/dsts before next tile
    }
}

// ================= fallback edge path =================
__global__ void copy_f4(const float4* __restrict__ src, float4* __restrict__ dst, int n4) {
    int i = blockIdx.x * blockDim.x + threadIdx.x;
    int stride = gridDim.x * blockDim.x;
    for (; i < n4; i += stride) dst[i] = src[i];
}

__global__ __launch_bounds__(128) void edge_kernel(
    const float* __restrict__ xin, const int* __restrict__ ei,
    const float* __restrict__ ea,  const float* __restrict__ We,
    const float* __restrict__ be,  float* __restrict__ agg)
{
    __shared__ float eas[ECHUNK * DE];
    const int t = threadIdx.x;
    float w[DE];
#pragma unroll
    for (int k = 0; k < DE; k++) w[k] = We[k * D + t];
    const float bias = be[t];
    const int nch = N_EDGES / ECHUNK;
    for (int ch = blockIdx.x; ch < nch; ch += gridDim.x) {
        const int e0 = ch * ECHUNK;
        ((float4*)eas)[t] = ((const float4*)(ea + (size_t)e0 * DE))[t];
        __syncthreads();
#pragma unroll
        for (int j = 0; j < ECHUNK; j++) {
            const int e = e0 + j;
            const int s = ei[e];
            const int d = ei[N_EDGES + e];
            float acc = bias;
            const float4* v4 = (const float4*)(eas + j * DE);
#pragma unroll
            for (int k4 = 0; k4 < DE / 4; k4++) {
                float4 v = v4[k4];
                acc += v.x * w[4 * k4 + 0];
                acc += v.y * w[4 * k4 + 1];
                acc += v.z * w[4 * k4 + 2];
                acc += v.w * w[4 * k4 + 3];
            }
            float msg = xin[(size_t)s * D + t] + acc;
            msg = msg > 0.f ? msg : 0.f;
            unsafeAtomicAdd(&agg[(size_t)d * D + t], msg);
        }
        __syncthreads();
    }
}

// ================= fused node MLP: 512 thr, 32-row tiles, 2 blocks/CU ======
// wave -> (rowg = wave&1 of 2 16-row groups, colq = wave>>2? no: wave>>1 of 4 col-quarters)
__global__ __launch_bounds__(512, 4) void mlp_kernel(
    float* __restrict__ io,
    const float* __restrict__ W1, const float* __restrict__ b1,
    const float* __restrict__ gamma, const float* __restrict__ beta,
    const float* __restrict__ rm,    const float* __restrict__ rv,
    const float* __restrict__ W2, const float* __restrict__ b2,
    float* __restrict__ agg2, int relu2)
{
    __shared__ __align__(16) unsigned short Wt1[D * LDST];   // 34816 B
    __shared__ __align__(16) unsigned short Wt2[D * LDST];   // 34816 B
    __shared__ __align__(16) unsigned short At[32 * LDST];   // 8704 B
    __shared__ float alpha_s[D], betac_s[D], b2_s[D];

    const int tid = threadIdx.x;
    for (int i = tid; i < D * (D / 4); i += 512) {
        const int k = i >> 5;
        const int n0 = (i & 31) * 4;
        float4 w = *(const float4*)(W1 + (size_t)k * D + n0);
        Wt1[(n0 + 0) * LDST + k] = f2bf(w.x);
        Wt1[(n0 + 1) * LDST + k] = f2bf(w.y);
        Wt1[(n0 + 2) * LDST + k] = f2bf(w.z);
        Wt1[(n0 + 3) * LDST + k] = f2bf(w.w);
        float4 u = *(const float4*)(W2 + (size_t)k * D + n0);
        Wt2[(n0 + 0) * LDST + k] = f2bf(u.x);
        Wt2[(n0 + 1) * LDST + k] = f2bf(u.y);
        Wt2[(n0 + 2) * LDST + k] = f2bf(u.z);
        Wt2[(n0 + 3) * LDST + k] = f2bf(u.w);
    }
    if (tid < D) {
        float a = gamma[tid] * rsqrtf(rv[tid] + BN_EPS);
        alpha_s[tid] = a;
        betac_s[tid] = beta[tid] + (b1[tid] - rm[tid]) * a;
        b2_s[tid] = b2[tid];
    }
    __syncthreads();

    const int wave = tid >> 6;
    const int lane = tid & 63;
    const int lrow = lane & 15;
    const int lquad = lane >> 4;
    const int rowg = wave & 1;      // 16-row group within 32-row tile
    const int colq = wave >> 1;     // col quarter: ct in {colq*2, colq*2+1}

    const int ntiles = (N_NODES + 31) / 32;   // 1563
    for (int g = blockIdx.x; g < ntiles; g += gridDim.x) {
        const int row0 = g * 32;
        for (int i = tid; i < 32 * (D / 4); i += 512) {   // 2 iters
            const int r = i >> 5;
            const int c0 = (i & 31) * 4;
            const int rr = row0 + r;
            float4 v = make_float4(0.f, 0.f, 0.f, 0.f);
            if (rr < N_NODES) v = *(const float4*)(io + (size_t)rr * D + c0);
            union { unsigned short s[4]; unsigned long long u; } p;
            p.s[0] = f2bf(v.x); p.s[1] = f2bf(v.y); p.s[2] = f2bf(v.z); p.s[3] = f2bf(v.w);
            *(unsigned long long*)&At[r * LDST + c0] = p.u;
        }
        __syncthreads();

        floatx4 acc[2];
#pragma unroll
        for (int q = 0; q < 2; q++) acc[q] = (floatx4){0.f, 0.f, 0.f, 0.f};
#pragma unroll
        for (int ks = 0; ks < 4; ks++) {
            short8 a = *(const short8*)&At[(rowg * 16 + lrow) * LDST + ks * 32 + lquad * 8];
#pragma unroll
            for (int q = 0; q < 2; q++) {
                const int ct = colq * 2 + q;
                short8 b = *(const short8*)&Wt1[(ct * 16 + lrow) * LDST + ks * 32 + lquad * 8];
                acc[q] = __builtin_amdgcn_mfma_f32_16x16x32_bf16(a, b, acc[q], 0, 0, 0);
            }
        }
        __syncthreads();   // all GEMM1 A-reads done before T1 overwrites At
#pragma unroll
        for (int q = 0; q < 2; q++) {
            const int c = (colq * 2 + q) * 16 + lrow;
            const float al = alpha_s[c], bt = betac_s[c];
#pragma unroll
            for (int j = 0; j < 4; j++) {
                const int r = rowg * 16 + lquad * 4 + j;
                float v = acc[q][j] * al + bt;
                v = v > 0.f ? v : 0.f;
                At[r * LDST + c] = f2bf(v);
            }
        }
        __syncthreads();

        floatx4 acc2[2];
#pragma unroll
        for (int q = 0; q < 2; q++) acc2[q] = (floatx4){0.f, 0.f, 0.f, 0.f};
#pragma unroll
        for (int ks = 0; ks < 4; ks++) {
            short8 a = *(const short8*)&At[(rowg * 16 + lrow) * LDST + ks * 32 + lquad * 8];
#pragma unroll
            for (int q = 0; q < 2; q++) {
                const int ct = colq * 2 + q;
                short8 b = *(const short8*)&Wt2[(ct * 16 + lrow) * LDST + ks * 32 + lquad * 8];
                acc2[q] = __builtin_amdgcn_mfma_f32_16x16x32_bf16(a, b, acc2[q], 0, 0, 0);
            }
        }
#pragma unroll
        for (int q = 0; q < 2; q++) {
            const int c = (colq * 2 + q) * 16 + lrow;
            const float bb = b2_s[c];
#pragma unroll
            for (int j = 0; j < 4; j++) {
                const int r = row0 + rowg * 16 + lquad * 4 + j;
                if (r < N_NODES) {
                    float v = acc2[q][j] + bb;
                    if (relu2) v = v > 0.f ? v : 0.f;
                    io[(size_t)r * D + c] = v;
                    if (agg2) agg2[(size_t)r * D + c] = v;
                }
            }
        }
        __syncthreads();
    }
}

// ================= pool (2-stage) =================
#define PB 1024
#define PC ((N_NODES + PB - 1) / PB)   // 49
__global__ __launch_bounds__(128) void pool_a(
    const float* __restrict__ xin, const int* __restrict__ batch,
    float* __restrict__ tmp)
{
    const int b = blockIdx.x, t = threadIdx.x;
    int n0 = b * PC;
    int n1 = n0 + PC; if (n1 > N_NODES) n1 = N_NODES;
    if (n0 >= n1) return;
    float s = 0.f;
    int gprev = batch[n0];
    for (int n = n0; n < n1; n++) {
        int g = batch[n];
        if (g != gprev) {
            unsafeAtomicAdd(&tmp[(size_t)gprev * D + t], s);
            s = 0.f; gprev = g;
        }
        s += xin[(size_t)n * D + t];
    }
    unsafeAtomicAdd(&tmp[(size_t)gprev * D + t], s);
}

__global__ __launch_bounds__(128) void pool_b(
    const float* __restrict__ tmp, const int* __restrict__ batch,
    float* __restrict__ out)
{
    const int g = blockIdx.x, t = threadIdx.x;
    int lo = 0, hi = N_NODES;
    while (lo < hi) { int m = (lo + hi) >> 1; if (batch[m] < g) lo = m + 1; else hi = m; }
    int lo2 = lo, hi2 = N_NODES;
    while (lo2 < hi2) { int m = (lo2 + hi2) >> 1; if (batch[m] < g + 1) lo2 = m + 1; else hi2 = m; }
    int cnt = lo2 - lo;
    out[(size_t)g * D + t] = tmp[(size_t)g * D + t] / (float)(cnt > 0 ? cnt : 1);
}

extern "C" void kernel_launch(void* const* d_in, const int* in_sizes, int n_in,
                              void* d_out, int out_size, void* d_ws, size_t ws_size,
                              hipStream_t stream) {
    const float* x     = (const float*)d_in[0];
    const int*   ei    = (const int*)  d_in[1];
    const float* ea    = (const float*)d_in[2];
    const int*   batch = (const int*)  d_in[3];
    const float* We    = (const float*)d_in[4];
    const float* be    = (const float*)d_in[5];
    const float* W1    = (const float*)d_in[6];
    const float* b1    = (const float*)d_in[7];
    const float* gamma = (const float*)d_in[8];
    const float* beta  = (const float*)d_in[9];
    const float* rm    = (const float*)d_in[10];
    const float* rv    = (const float*)d_in[11];
    const float* W2    = (const float*)d_in[12];
    const float* b2    = (const float*)d_in[13];
    float* out = (float*)d_out;

    char* ws = (char*)d_ws;
    size_t o = 0;
    auto alloc = [&](size_t bytes) -> char* {
        char* p = ws + o; o = (o + bytes + 255) & ~(size_t)255; return p;
    };
    float* bufA  = (float*)alloc((size_t)N_NODES * D * 4);
    float* bufB  = (float*)alloc((size_t)N_NODES * D * 4);
    int* deg     = (int*)alloc((size_t)N_NODES * 4);
    int* off     = (int*)alloc((size_t)(N_NODES + 1) * 4);
    int* cursor  = (int*)alloc((size_t)N_NODES * 4);
    int* perm    = (int*)alloc((size_t)N_EDGES * 4);
    int* srcp    = (int*)alloc((size_t)N_EDGES * 4);
    int* dstp    = (int*)alloc((size_t)N_EDGES * 4);
    int* bsum    = (int*)alloc(256 * 4);
    float* ptmp  = (float*)alloc((size_t)N_GRAPHS * D * 4);
    const size_t needSorted = o;
    unsigned short* eap = nullptr;
    if (ws_size >= needSorted + (size_t)N_EDGES * DE * 2)
        eap = (unsigned short*)(ws + needSorted);
    const bool sorted = (ws_size >= needSorted);

    const int NB = (N_NODES + 255) / 256;   // 196

    if (sorted) {
        hipMemsetAsync(deg, 0, (size_t)N_NODES * 4, stream);
        hipMemsetAsync(ptmp, 0, (size_t)N_GRAPHS * D * 4, stream);
        hist_kernel<<<(N_EDGES + 255) / 256, 256, 0, stream>>>(ei, deg);
        scan1_kernel<<<NB, 256, 0, stream>>>(deg, bsum);
        scan2_kernel<<<1, 256, 0, stream>>>(bsum, NB);
        scan3_kernel<<<NB, 256, 0, stream>>>(deg, bsum, off, cursor);
        permute_kernel<<<(N_EDGES + 255) / 256, 256, 0, stream>>>(ei, cursor, perm, srcp, dstp);
        if (eap) eap_kernel<<<(N_EDGES * 16 + 255) / 256, 256, 0, stream>>>(ea, perm, eap);

        const float* cur = x;
        float* agg = bufA;
        float* nxtAgg = bufB;
        copy_f4<<<1024, 256, 0, stream>>>((const float4*)x, (float4*)agg, N_NODES * D / 4);
        for (int i = 0; i < N_LAYERS; i++) {
            edge_fused<<<1024, 512, 0, stream>>>(cur, ea, eap, perm, srcp, dstp,
                                                 We + (size_t)i * DE * D, be + (size_t)i * D,
                                                 agg, eap ? 1 : 0);
            mlp_kernel<<<512, 512, 0, stream>>>(agg,
                W1 + (size_t)i * D * D, b1 + (size_t)i * D,
                gamma + (size_t)i * D, beta + (size_t)i * D,
                rm + (size_t)i * D, rv + (size_t)i * D,
                W2 + (size_t)i * D * D, b2 + (size_t)i * D,
                (i != N_LAYERS - 1) ? nxtAgg : nullptr,
                (i != N_LAYERS - 1) ? 1 : 0);
            cur = agg;
            agg = nxtAgg;
            nxtAgg = (float*)cur;
        }
        pool_a<<<PB, 128, 0, stream>>>(cur, batch, ptmp);
        pool_b<<<N_GRAPHS, 128, 0, stream>>>(ptmp, batch, out);
    } else {
        const float* cur = x;
        float* nxt = bufA;
        for (int i = 0; i < N_LAYERS; i++) {
            copy_f4<<<1024, 256, 0, stream>>>((const float4*)cur, (float4*)nxt, N_NODES * D / 4);
            edge_kernel<<<4096, 128, 0, stream>>>(cur, ei, ea, We + (size_t)i * DE * D, be + (size_t)i * D, nxt);
            mlp_kernel<<<512, 512, 0, stream>>>(nxt,
                W1 + (size_t)i * D * D, b1 + (size_t)i * D,
                gamma + (size_t)i * D, beta + (size_t)i * D,
                rm + (size_t)i * D, rv + (size_t)i * D,
                W2 + (size_t)i * D * D, b2 + (size_t)i * D,
                nullptr, (i != N_LAYERS - 1) ? 1 : 0);
            cur = nxt;
            nxt = (nxt == bufA) ? bufB : bufA;
        }
        hipMemsetAsync(ptmp, 0, (size_t)N_GRAPHS * D * 4, stream);
        pool_a<<<PB, 128, 0, stream>>>(cur, batch, ptmp);
        pool_b<<<N_GRAPHS, 128, 0, stream>>>(ptmp, batch, out);
    }
}

// Round 6
// 840.596 us; speedup vs baseline: 2.1490x; 1.0431x over previous
//
#include <hip/hip_runtime.h>

#define N_NODES 50000
#define N_EDGES 600000
#define N_GRAPHS 128
#define D 128
#define DE 64
#define N_LAYERS 4
#define BN_EPS 1e-5f
#define ECHUNK 8
#define LDST 136   // mlp/T1 LDS stride (bf16): 272 B rows, 16B-aligned
#define WST 72     // K=64 LDS stride (bf16): 144 B rows, 16B-aligned
#define CTS 132    // edge C-tile stride (bf16)
#define ET 128     // edges per tile

typedef __attribute__((ext_vector_type(8))) short short8;
typedef __attribute__((ext_vector_type(4))) float floatx4;
typedef unsigned long long u64;

__device__ __forceinline__ unsigned short f2bf(float f) {
    union { float f; unsigned u; } v; v.f = f;
    unsigned r = v.u + 0x7FFF + ((v.u >> 16) & 1);  // RNE
    return (unsigned short)(r >> 16);
}
__device__ __forceinline__ float bf2f(unsigned short h) {
    union { unsigned u; float f; } v; v.u = ((unsigned)h) << 16; return v.f;
}

// ================= setup: dst-sort =================
__global__ void hist_kernel(const int* __restrict__ ei, int* __restrict__ deg) {
    int e = blockIdx.x * 256 + threadIdx.x;
    if (e < N_EDGES) atomicAdd(&deg[ei[N_EDGES + e]], 1);
}

__global__ void scan1_kernel(const int* __restrict__ deg, int* __restrict__ bsum) {
    __shared__ int s[256];
    int t = threadIdx.x, i = blockIdx.x * 256 + t;
    s[t] = (i < N_NODES) ? deg[i] : 0;
    __syncthreads();
    for (int d = 128; d > 0; d >>= 1) {
        if (t < d) s[t] += s[t + d];
        __syncthreads();
    }
    if (t == 0) bsum[blockIdx.x] = s[0];
}

__global__ void scan2_kernel(int* __restrict__ bsum, int nb) {
    __shared__ int s[256];
    int t = threadIdx.x;
    int v = (t < nb) ? bsum[t] : 0;
    s[t] = v;
    __syncthreads();
    for (int d = 1; d < 256; d <<= 1) {
        int u = (t >= d) ? s[t - d] : 0;
        __syncthreads();
        s[t] += u;
        __syncthreads();
    }
    if (t < nb) bsum[t] = s[t] - v;   // exclusive
}

__global__ void scan3_kernel(const int* __restrict__ deg, const int* __restrict__ bsum,
                             int* __restrict__ off, int* __restrict__ cursor) {
    __shared__ int s[256];
    int t = threadIdx.x, i = blockIdx.x * 256 + t;
    int v = (i < N_NODES) ? deg[i] : 0;
    s[t] = v;
    __syncthreads();
    for (int d = 1; d < 256; d <<= 1) {
        int u = (t >= d) ? s[t - d] : 0;
        __syncthreads();
        s[t] += u;
        __syncthreads();
    }
    if (i < N_NODES) {
        int o = bsum[blockIdx.x] + s[t] - v;
        off[i] = o; cursor[i] = o;
    }
    if (i == N_NODES - 1) off[N_NODES] = bsum[blockIdx.x] + s[t];
}

__global__ void permute_kernel(const int* __restrict__ ei, int* __restrict__ cursor,
                               int* __restrict__ perm, int* __restrict__ srcp,
                               int* __restrict__ dstp) {
    int e = blockIdx.x * 256 + threadIdx.x;
    if (e < N_EDGES) {
        int d = ei[N_EDGES + e];
        int p = atomicAdd(&cursor[d], 1);
        perm[p] = e; srcp[p] = ei[e]; dstp[p] = d;
    }
}

// dst-sorted bf16 edge_attr
__global__ void eap_kernel(const float* __restrict__ ea, const int* __restrict__ perm,
                           unsigned short* __restrict__ eap) {
    int i = blockIdx.x * 256 + threadIdx.x;
    if (i >= N_EDGES * 16) return;
    int p = i >> 4, c0 = (i & 15) * 4;
    int e = perm[p];
    float4 v = *(const float4*)(ea + (size_t)e * DE + c0);
    union { unsigned short s[4]; u64 u; } pk;
    pk.s[0] = f2bf(v.x); pk.s[1] = f2bf(v.y); pk.s[2] = f2bf(v.z); pk.s[3] = f2bf(v.w);
    *(u64*)(eap + (size_t)p * DE + c0) = pk.u;
}

// init: aggA = x (fp32), xbA = bf16(x)
__global__ void init_kernel(const float* __restrict__ x, float* __restrict__ agg,
                            unsigned short* __restrict__ xb) {
    int i = blockIdx.x * 256 + threadIdx.x;
    int stride = gridDim.x * 256;
    for (; i < N_NODES * D / 4; i += stride) {
        float4 v = ((const float4*)x)[i];
        ((float4*)agg)[i] = v;
        union { unsigned short s[4]; u64 u; } pk;
        pk.s[0] = f2bf(v.x); pk.s[1] = f2bf(v.y); pk.s[2] = f2bf(v.z); pk.s[3] = f2bf(v.w);
        *(u64*)(xb + (size_t)i * 4) = pk.u;
    }
}

// ================= fused edge layer =================
// agg[dst] += relu(x[src] + ea@We + be) over dst-sorted 128-edge tiles.
// 512 thr / 8 waves; wave owns 16 rows; eap-tile prefetch; bf16 or fp32 gather.
__global__ __launch_bounds__(512, 4) void edge_fused(
    const unsigned short* __restrict__ xb,   // bf16 gather source (nullable)
    const float* __restrict__ xf,            // fp32 gather source (if xb null)
    const unsigned short* __restrict__ eap,
    const float* __restrict__ ea,
    const int* __restrict__ perm,
    const int* __restrict__ srcp,
    const int* __restrict__ dstp,
    const float* __restrict__ We, const float* __restrict__ be,
    float* __restrict__ agg, int useEap)
{
    __shared__ __align__(16) unsigned short Wt[D * WST];
    __shared__ __align__(16) unsigned short As[ET * WST];
    __shared__ __align__(16) unsigned short Ct[ET * CTS];
    __shared__ int srcs[ET];
    __shared__ int dsts[ET];
    __shared__ float be_s[D];

    const int tid = threadIdx.x;
    for (int i = tid; i < DE * (D / 4); i += 512) {
        int k = i >> 5, n0 = (i & 31) * 4;
        float4 w = *(const float4*)(We + (size_t)k * D + n0);
        Wt[(n0 + 0) * WST + k] = f2bf(w.x);
        Wt[(n0 + 1) * WST + k] = f2bf(w.y);
        Wt[(n0 + 2) * WST + k] = f2bf(w.z);
        Wt[(n0 + 3) * WST + k] = f2bf(w.w);
    }
    if (tid < D) be_s[tid] = be[tid];

    const int wave = tid >> 6, lane = tid & 63;
    const int lrow = lane & 15, lquad = lane >> 4;
    const int cp = lane;                 // col pair {2cp, 2cp+1}
    const int ntiles = (N_EDGES + ET - 1) / ET;

    // tile body: MFMA + bias -> Ct, then segmented accumulate
    auto body = [&](int nv) {
        const int rlo = wave * 16;
        floatx4 acc[8];
#pragma unroll
        for (int ct = 0; ct < 8; ct++) acc[ct] = (floatx4){0.f, 0.f, 0.f, 0.f};
#pragma unroll
        for (int ks = 0; ks < 2; ks++) {
            short8 a = *(const short8*)&As[(rlo + lrow) * WST + ks * 32 + lquad * 8];
#pragma unroll
            for (int ct = 0; ct < 8; ct++) {
                short8 b = *(const short8*)&Wt[(ct * 16 + lrow) * WST + ks * 32 + lquad * 8];
                acc[ct] = __builtin_amdgcn_mfma_f32_16x16x32_bf16(a, b, acc[ct], 0, 0, 0);
            }
        }
#pragma unroll
        for (int ct = 0; ct < 8; ct++) {
            const int c = ct * 16 + lrow;
            const float bb = be_s[c];
#pragma unroll
            for (int j = 0; j < 4; j++) {
                const int r = rlo + lquad * 4 + j;
                Ct[r * CTS + c] = f2bf(acc[ct][j] + bb);
            }
        }
        // wave reads back only its own Ct rows: within-wave lgkmcnt handles RAW
        if (rlo < nv) {
            unsigned ed[16];
#pragma unroll
            for (int j = 0; j < 16; j++)
                ed[j] = *(const unsigned*)&Ct[(rlo + j) * CTS + 2 * cp];
            float a0 = 0.f, a1 = 0.f;
            int dprev = dsts[rlo];
            if (xb) {
                unsigned xu[16];
#pragma unroll
                for (int j = 0; j < 16; j++)
                    xu[j] = *(const unsigned*)(xb + (size_t)srcs[rlo + j] * D + 2 * cp);
#pragma unroll
                for (int j = 0; j < 16; j++) {
                    float v0 = bf2f((unsigned short)(xu[j] & 0xFFFF)) + bf2f((unsigned short)(ed[j] & 0xFFFF));
                    float v1 = bf2f((unsigned short)(xu[j] >> 16)) + bf2f((unsigned short)(ed[j] >> 16));
                    a0 += v0 > 0.f ? v0 : 0.f;
                    a1 += v1 > 0.f ? v1 : 0.f;
                    int dnext = (j < 15) ? dsts[rlo + j + 1] : -2;
                    if (dnext != dprev) {
                        float* ap = agg + (size_t)dprev * D + 2 * cp;
                        unsafeAtomicAdd(ap, a0);
                        unsafeAtomicAdd(ap + 1, a1);
                        a0 = 0.f; a1 = 0.f;
                        dprev = dnext;
                    }
                }
            } else {
                float2 xv[16];
#pragma unroll
                for (int j = 0; j < 16; j++)
                    xv[j] = *(const float2*)(xf + (size_t)srcs[rlo + j] * D + 2 * cp);
#pragma unroll
                for (int j = 0; j < 16; j++) {
                    float v0 = xv[j].x + bf2f((unsigned short)(ed[j] & 0xFFFF));
                    float v1 = xv[j].y + bf2f((unsigned short)(ed[j] >> 16));
                    a0 += v0 > 0.f ? v0 : 0.f;
                    a1 += v1 > 0.f ? v1 : 0.f;
                    int dnext = (j < 15) ? dsts[rlo + j + 1] : -2;
                    if (dnext != dprev) {
                        float* ap = agg + (size_t)dprev * D + 2 * cp;
                        unsafeAtomicAdd(ap, a0);
                        unsafeAtomicAdd(ap + 1, a1);
                        a0 = 0.f; a1 = 0.f;
                        dprev = dnext;
                    }
                }
            }
        }
    };

    if (useEap) {
        u64 pfA[4];
        int pfS = 0, pfD = -1;
        auto ldt = [&](int gg) {
            if (gg < ntiles) {
                const int p0 = gg * ET;
                const int nv = (N_EDGES - p0 < ET) ? (N_EDGES - p0) : ET;
#pragma unroll
                for (int it = 0; it < 4; it++) {
                    int i = tid + it * 512;
                    int r = i >> 4, c0 = (i & 15) * 4;
                    pfA[it] = (r < nv) ? *(const u64*)(eap + (size_t)(p0 + r) * DE + c0) : 0ULL;
                }
                if (tid < ET) {
                    bool ok = tid < nv;
                    pfS = ok ? srcp[p0 + tid] : 0;
                    pfD = ok ? dstp[p0 + tid] : -1;
                }
            }
        };
        ldt(blockIdx.x);
        for (int g = blockIdx.x; g < ntiles; g += gridDim.x) {
#pragma unroll
            for (int it = 0; it < 4; it++) {
                int i = tid + it * 512;
                int r = i >> 4, c0 = (i & 15) * 4;
                *(u64*)&As[r * WST + c0] = pfA[it];
            }
            if (tid < ET) { srcs[tid] = pfS; dsts[tid] = pfD; }
            __syncthreads();
            ldt(g + gridDim.x);   // next tile's loads in flight during compute
            const int p0 = g * ET;
            const int nv = (N_EDGES - p0 < ET) ? (N_EDGES - p0) : ET;
            body(nv);
            __syncthreads();
        }
    } else {
        for (int g = blockIdx.x; g < ntiles; g += gridDim.x) {
            const int p0 = g * ET;
            const int nv = (N_EDGES - p0 < ET) ? (N_EDGES - p0) : ET;
            if (tid < ET) {
                bool ok = tid < nv;
                srcs[tid] = ok ? srcp[p0 + tid] : 0;
                dsts[tid] = ok ? dstp[p0 + tid] : -1;
            }
            for (int i = tid; i < ET * 16; i += 512) {
                int r = i >> 4, c0 = (i & 15) * 4;
                float4 v = make_float4(0.f, 0.f, 0.f, 0.f);
                if (r < nv) {
                    int e = perm[p0 + r];
                    v = *(const float4*)(ea + (size_t)e * DE + c0);
                }
                union { unsigned short s[4]; u64 u; } pk;
                pk.s[0] = f2bf(v.x); pk.s[1] = f2bf(v.y); pk.s[2] = f2bf(v.z); pk.s[3] = f2bf(v.w);
                *(u64*)&As[r * WST + c0] = pk.u;
            }
            __syncthreads();
            body(nv);
            __syncthreads();
        }
    }
}

// ================= fallback edge path (unsorted) =================
__global__ void copy_f4(const float4* __restrict__ src, float4* __restrict__ dst, int n4) {
    int i = blockIdx.x * blockDim.x + threadIdx.x;
    int stride = gridDim.x * blockDim.x;
    for (; i < n4; i += stride) dst[i] = src[i];
}

__global__ __launch_bounds__(128) void edge_kernel(
    const float* __restrict__ xin, const int* __restrict__ ei,
    const float* __restrict__ ea,  const float* __restrict__ We,
    const float* __restrict__ be,  float* __restrict__ agg)
{
    __shared__ float eas[ECHUNK * DE];
    const int t = threadIdx.x;
    float w[DE];
#pragma unroll
    for (int k = 0; k < DE; k++) w[k] = We[k * D + t];
    const float bias = be[t];
    const int nch = N_EDGES / ECHUNK;
    for (int ch = blockIdx.x; ch < nch; ch += gridDim.x) {
        const int e0 = ch * ECHUNK;
        ((float4*)eas)[t] = ((const float4*)(ea + (size_t)e0 * DE))[t];
        __syncthreads();
#pragma unroll
        for (int j = 0; j < ECHUNK; j++) {
            const int e = e0 + j;
            const int s = ei[e];
            const int d = ei[N_EDGES + e];
            float acc = bias;
            const float4* v4 = (const float4*)(eas + j * DE);
#pragma unroll
            for (int k4 = 0; k4 < DE / 4; k4++) {
                float4 v = v4[k4];
                acc += v.x * w[4 * k4 + 0];
                acc += v.y * w[4 * k4 + 1];
                acc += v.z * w[4 * k4 + 2];
                acc += v.w * w[4 * k4 + 3];
            }
            float msg = xin[(size_t)s * D + t] + acc;
            msg = msg > 0.f ? msg : 0.f;
            unsafeAtomicAdd(&agg[(size_t)d * D + t], msg);
        }
        __syncthreads();
    }
}

// ================= fused node MLP v2: global A-frags + prefetch, 2 barriers/tile ======
// 512 thr / 8 waves; 32-row tiles; rowg=wave&1, colq=wave>>1 (2 ct each).
__global__ __launch_bounds__(512, 4) void mlp2_kernel(
    const float* __restrict__ aggIn,
    float* __restrict__ fOut,            // fp32 out (nullable; may == aggIn)
    float* __restrict__ aggOut,          // fp32 out (nullable)
    unsigned short* __restrict__ xbOut,  // bf16 out (nullable)
    const float* __restrict__ W1, const float* __restrict__ b1,
    const float* __restrict__ gamma, const float* __restrict__ beta,
    const float* __restrict__ rm,    const float* __restrict__ rv,
    const float* __restrict__ W2, const float* __restrict__ b2,
    int relu2)
{
    __shared__ __align__(16) unsigned short Wt1[D * LDST];   // 34816 B
    __shared__ __align__(16) unsigned short Wt2[D * LDST];   // 34816 B
    __shared__ __align__(16) unsigned short T1[32 * LDST];   // 8704 B
    __shared__ float alpha_s[D], betac_s[D], b2_s[D];

    const int tid = threadIdx.x;
    for (int i = tid; i < D * (D / 4); i += 512) {
        const int k = i >> 5;
        const int n0 = (i & 31) * 4;
        float4 w = *(const float4*)(W1 + (size_t)k * D + n0);
        Wt1[(n0 + 0) * LDST + k] = f2bf(w.x);
        Wt1[(n0 + 1) * LDST + k] = f2bf(w.y);
        Wt1[(n0 + 2) * LDST + k] = f2bf(w.z);
        Wt1[(n0 + 3) * LDST + k] = f2bf(w.w);
        float4 u = *(const float4*)(W2 + (size_t)k * D + n0);
        Wt2[(n0 + 0) * LDST + k] = f2bf(u.x);
        Wt2[(n0 + 1) * LDST + k] = f2bf(u.y);
        Wt2[(n0 + 2) * LDST + k] = f2bf(u.z);
        Wt2[(n0 + 3) * LDST + k] = f2bf(u.w);
    }
    if (tid < D) {
        float a = gamma[tid] * rsqrtf(rv[tid] + BN_EPS);
        alpha_s[tid] = a;
        betac_s[tid] = beta[tid] + (b1[tid] - rm[tid]) * a;
        b2_s[tid] = b2[tid];
    }
    __syncthreads();

    const int wave = tid >> 6;
    const int lane = tid & 63;
    const int lrow = lane & 15;
    const int lquad = lane >> 4;
    const int rowg = wave & 1;      // 16-row group within 32-row tile
    const int colq = wave >> 1;     // col quarter: ct in {colq*2, colq*2+1}

    const int ntiles = (N_NODES + 31) / 32;   // 1563
    float4 Af[8];
    auto pf = [&](int gg) {
        if (gg < ntiles) {
            const int r = gg * 32 + rowg * 16 + lrow;
            const bool ok = r < N_NODES;
            const float* p = aggIn + (size_t)r * D;
#pragma unroll
            for (int ks = 0; ks < 4; ks++) {
                Af[2 * ks + 0] = ok ? *(const float4*)(p + ks * 32 + lquad * 8 + 0) : make_float4(0.f, 0.f, 0.f, 0.f);
                Af[2 * ks + 1] = ok ? *(const float4*)(p + ks * 32 + lquad * 8 + 4) : make_float4(0.f, 0.f, 0.f, 0.f);
            }
        }
    };
    pf(blockIdx.x);

    for (int g = blockIdx.x; g < ntiles; g += gridDim.x) {
        // convert prefetched A rows to bf16 frags
        short8 a[4];
#pragma unroll
        for (int ks = 0; ks < 4; ks++) {
            union { unsigned short s[8]; short8 v; } pk;
            pk.s[0] = f2bf(Af[2 * ks].x); pk.s[1] = f2bf(Af[2 * ks].y);
            pk.s[2] = f2bf(Af[2 * ks].z); pk.s[3] = f2bf(Af[2 * ks].w);
            pk.s[4] = f2bf(Af[2 * ks + 1].x); pk.s[5] = f2bf(Af[2 * ks + 1].y);
            pk.s[6] = f2bf(Af[2 * ks + 1].z); pk.s[7] = f2bf(Af[2 * ks + 1].w);
            a[ks] = pk.v;
        }
        pf(g + gridDim.x);   // next tile's loads in flight across both GEMMs

        floatx4 acc[2];
#pragma unroll
        for (int q = 0; q < 2; q++) acc[q] = (floatx4){0.f, 0.f, 0.f, 0.f};
#pragma unroll
        for (int ks = 0; ks < 4; ks++) {
#pragma unroll
            for (int q = 0; q < 2; q++) {
                const int ct = colq * 2 + q;
                short8 b = *(const short8*)&Wt1[(ct * 16 + lrow) * LDST + ks * 32 + lquad * 8];
                acc[q] = __builtin_amdgcn_mfma_f32_16x16x32_bf16(a[ks], b, acc[q], 0, 0, 0);
            }
        }
        // epilogue 1 -> T1 (prev tile's GEMM2 reads finished at loop-end barrier)
#pragma unroll
        for (int q = 0; q < 2; q++) {
            const int c = (colq * 2 + q) * 16 + lrow;
            const float al = alpha_s[c], bt = betac_s[c];
#pragma unroll
            for (int j = 0; j < 4; j++) {
                const int r = rowg * 16 + lquad * 4 + j;
                float v = acc[q][j] * al + bt;
                v = v > 0.f ? v : 0.f;
                T1[r * LDST + c] = f2bf(v);
            }
        }
        __syncthreads();

        floatx4 acc2[2];
#pragma unroll
        for (int q = 0; q < 2; q++) acc2[q] = (floatx4){0.f, 0.f, 0.f, 0.f};
#pragma unroll
        for (int ks = 0; ks < 4; ks++) {
            short8 a2 = *(const short8*)&T1[(rowg * 16 + lrow) * LDST + ks * 32 + lquad * 8];
#pragma unroll
            for (int q = 0; q < 2; q++) {
                const int ct = colq * 2 + q;
                short8 b = *(const short8*)&Wt2[(ct * 16 + lrow) * LDST + ks * 32 + lquad * 8];
                acc2[q] = __builtin_amdgcn_mfma_f32_16x16x32_bf16(a2, b, acc2[q], 0, 0, 0);
            }
        }
#pragma unroll
        for (int q = 0; q < 2; q++) {
            const int c = (colq * 2 + q) * 16 + lrow;
            const float bb = b2_s[c];
#pragma unroll
            for (int j = 0; j < 4; j++) {
                const int r = g * 32 + rowg * 16 + lquad * 4 + j;
                if (r < N_NODES) {
                    float v = acc2[q][j] + bb;
                    if (relu2) v = v > 0.f ? v : 0.f;
                    if (fOut)   fOut[(size_t)r * D + c] = v;
                    if (aggOut) aggOut[(size_t)r * D + c] = v;
                    if (xbOut)  xbOut[(size_t)r * D + c] = f2bf(v);
                }
            }
        }
        __syncthreads();
    }
}

// ================= pool (2-stage) =================
#define PB 1024
#define PC ((N_NODES + PB - 1) / PB)   // 49
__global__ __launch_bounds__(128) void pool_a_bf(
    const unsigned short* __restrict__ xb, const int* __restrict__ batch,
    float* __restrict__ tmp)
{
    const int b = blockIdx.x, t = threadIdx.x;
    int n0 = b * PC;
    int n1 = n0 + PC; if (n1 > N_NODES) n1 = N_NODES;
    if (n0 >= n1) return;
    float s = 0.f;
    int gprev = batch[n0];
    for (int n = n0; n < n1; n++) {
        int g = batch[n];
        if (g != gprev) {
            unsafeAtomicAdd(&tmp[(size_t)gprev * D + t], s);
            s = 0.f; gprev = g;
        }
        s += bf2f(xb[(size_t)n * D + t]);
    }
    unsafeAtomicAdd(&tmp[(size_t)gprev * D + t], s);
}

__global__ __launch_bounds__(128) void pool_a(
    const float* __restrict__ xin, const int* __restrict__ batch,
    float* __restrict__ tmp)
{
    const int b = blockIdx.x, t = threadIdx.x;
    int n0 = b * PC;
    int n1 = n0 + PC; if (n1 > N_NODES) n1 = N_NODES;
    if (n0 >= n1) return;
    float s = 0.f;
    int gprev = batch[n0];
    for (int n = n0; n < n1; n++) {
        int g = batch[n];
        if (g != gprev) {
            unsafeAtomicAdd(&tmp[(size_t)gprev * D + t], s);
            s = 0.f; gprev = g;
        }
        s += xin[(size_t)n * D + t];
    }
    unsafeAtomicAdd(&tmp[(size_t)gprev * D + t], s);
}

__global__ __launch_bounds__(128) void pool_b(
    const float* __restrict__ tmp, const int* __restrict__ batch,
    float* __restrict__ out)
{
    const int g = blockIdx.x, t = threadIdx.x;
    int lo = 0, hi = N_NODES;
    while (lo < hi) { int m = (lo + hi) >> 1; if (batch[m] < g) lo = m + 1; else hi = m; }
    int lo2 = lo, hi2 = N_NODES;
    while (lo2 < hi2) { int m = (lo2 + hi2) >> 1; if (batch[m] < g + 1) lo2 = m + 1; else hi2 = m; }
    int cnt = lo2 - lo;
    out[(size_t)g * D + t] = tmp[(size_t)g * D + t] / (float)(cnt > 0 ? cnt : 1);
}

extern "C" void kernel_launch(void* const* d_in, const int* in_sizes, int n_in,
                              void* d_out, int out_size, void* d_ws, size_t ws_size,
                              hipStream_t stream) {
    const float* x     = (const float*)d_in[0];
    const int*   ei    = (const int*)  d_in[1];
    const float* ea    = (const float*)d_in[2];
    const int*   batch = (const int*)  d_in[3];
    const float* We    = (const float*)d_in[4];
    const float* be    = (const float*)d_in[5];
    const float* W1    = (const float*)d_in[6];
    const float* b1    = (const float*)d_in[7];
    const float* gamma = (const float*)d_in[8];
    const float* beta  = (const float*)d_in[9];
    const float* rm    = (const float*)d_in[10];
    const float* rv    = (const float*)d_in[11];
    const float* W2    = (const float*)d_in[12];
    const float* b2    = (const float*)d_in[13];
    float* out = (float*)d_out;

    char* ws = (char*)d_ws;
    size_t o = 0;
    auto alloc = [&](size_t bytes) -> char* {
        char* p = ws + o; o = (o + bytes + 255) & ~(size_t)255; return p;
    };
    float* aggA  = (float*)alloc((size_t)N_NODES * D * 4);
    float* aggB  = (float*)alloc((size_t)N_NODES * D * 4);
    int* deg     = (int*)alloc((size_t)N_NODES * 4);
    int* off     = (int*)alloc((size_t)(N_NODES + 1) * 4);
    int* cursor  = (int*)alloc((size_t)N_NODES * 4);
    int* perm    = (int*)alloc((size_t)N_EDGES * 4);
    int* srcp    = (int*)alloc((size_t)N_EDGES * 4);
    int* dstp    = (int*)alloc((size_t)N_EDGES * 4);
    int* bsum    = (int*)alloc(256 * 4);
    float* ptmp  = (float*)alloc((size_t)N_GRAPHS * D * 4);
    const size_t needSorted = o;
    unsigned short* eap = (unsigned short*)alloc((size_t)N_EDGES * DE * 2);
    const size_t needEap = o;
    unsigned short* xbA = (unsigned short*)alloc((size_t)N_NODES * D * 2);
    unsigned short* xbB = (unsigned short*)alloc((size_t)N_NODES * D * 2);
    const size_t needXb = o;

    const bool sorted = (ws_size >= needSorted);
    const int useEap  = (ws_size >= needEap) ? 1 : 0;
    const bool useXb  = (ws_size >= needXb);

    const int NB = (N_NODES + 255) / 256;   // 196

    if (sorted) {
        hipMemsetAsync(deg, 0, (size_t)N_NODES * 4, stream);
        hipMemsetAsync(ptmp, 0, (size_t)N_GRAPHS * D * 4, stream);
        hist_kernel<<<(N_EDGES + 255) / 256, 256, 0, stream>>>(ei, deg);
        scan1_kernel<<<NB, 256, 0, stream>>>(deg, bsum);
        scan2_kernel<<<1, 256, 0, stream>>>(bsum, NB);
        scan3_kernel<<<NB, 256, 0, stream>>>(deg, bsum, off, cursor);
        permute_kernel<<<(N_EDGES + 255) / 256, 256, 0, stream>>>(ei, cursor, perm, srcp, dstp);
        if (useEap) eap_kernel<<<(N_EDGES * 16 + 255) / 256, 256, 0, stream>>>(ea, perm, eap);

        if (useXb) {
            init_kernel<<<2048, 256, 0, stream>>>(x, aggA, xbA);
            float* curAgg = aggA; unsigned short* curXb = xbA;
            float* nxtAgg = aggB; unsigned short* nxtXb = xbB;
            for (int i = 0; i < N_LAYERS; i++) {
                const int last = (i == N_LAYERS - 1);
                edge_fused<<<512, 512, 0, stream>>>(curXb, nullptr, eap, ea, perm, srcp, dstp,
                                                    We + (size_t)i * DE * D, be + (size_t)i * D,
                                                    curAgg, useEap);
                mlp2_kernel<<<512, 512, 0, stream>>>(curAgg, nullptr,
                    last ? nullptr : nxtAgg, nxtXb,
                    W1 + (size_t)i * D * D, b1 + (size_t)i * D,
                    gamma + (size_t)i * D, beta + (size_t)i * D,
                    rm + (size_t)i * D, rv + (size_t)i * D,
                    W2 + (size_t)i * D * D, b2 + (size_t)i * D, last ? 0 : 1);
                float* ta = curAgg; curAgg = nxtAgg; nxtAgg = ta;
                unsigned short* tx = curXb; curXb = nxtXb; nxtXb = tx;
            }
            pool_a_bf<<<PB, 128, 0, stream>>>(curXb, batch, ptmp);
            pool_b<<<N_GRAPHS, 128, 0, stream>>>(ptmp, batch, out);
        } else {
            copy_f4<<<1024, 256, 0, stream>>>((const float4*)x, (float4*)aggA, N_NODES * D / 4);
            const float* xfCur = x;
            float* curAgg = aggA; float* othAgg = aggB;
            for (int i = 0; i < N_LAYERS; i++) {
                const int last = (i == N_LAYERS - 1);
                edge_fused<<<512, 512, 0, stream>>>(nullptr, xfCur, eap, ea, perm, srcp, dstp,
                                                    We + (size_t)i * DE * D, be + (size_t)i * D,
                                                    curAgg, useEap);
                mlp2_kernel<<<512, 512, 0, stream>>>(curAgg, curAgg,
                    last ? nullptr : othAgg, nullptr,
                    W1 + (size_t)i * D * D, b1 + (size_t)i * D,
                    gamma + (size_t)i * D, beta + (size_t)i * D,
                    rm + (size_t)i * D, rv + (size_t)i * D,
                    W2 + (size_t)i * D * D, b2 + (size_t)i * D, last ? 0 : 1);
                xfCur = curAgg;
                float* t = curAgg; curAgg = othAgg; othAgg = t;
            }
            pool_a<<<PB, 128, 0, stream>>>(xfCur, batch, ptmp);
            pool_b<<<N_GRAPHS, 128, 0, stream>>>(ptmp, batch, out);
        }
    } else {
        hipMemsetAsync(ptmp, 0, (size_t)N_GRAPHS * D * 4, stream);
        const float* cur = x;
        float* nxt = aggA;
        for (int i = 0; i < N_LAYERS; i++) {
            copy_f4<<<1024, 256, 0, stream>>>((const float4*)cur, (float4*)nxt, N_NODES * D / 4);
            edge_kernel<<<4096, 128, 0, stream>>>(cur, ei, ea, We + (size_t)i * DE * D, be + (size_t)i * D, nxt);
            mlp2_kernel<<<512, 512, 0, stream>>>(nxt, nxt, nullptr, nullptr,
                W1 + (size_t)i * D * D, b1 + (size_t)i * D,
                gamma + (size_t)i * D, beta + (size_t)i * D,
                rm + (size_t)i * D, rv + (size_t)i * D,
                W2 + (size_t)i * D * D, b2 + (size_t)i * D,
                (i != N_LAYERS - 1) ? 1 : 0);
            cur = nxt;
            nxt = (nxt == aggA) ? aggB : aggA;
        }
        pool_a<<<PB, 128, 0, stream>>>(cur, batch, ptmp);
        pool_b<<<N_GRAPHS, 128, 0, stream>>>(ptmp, batch, out);
    }
}